// Round 4
// baseline (5283.143 us; speedup 1.0000x reference)
//
#include <hip/hip_runtime.h>
#include <math.h>

// Problem constants: D=3, H=64, WIN=8, OUT=32, B=128, T=129
#define BB 128
#define TT 129
#define NSTEP 128
#define NW 16
#define WINW 8
#define OUTD 32

typedef _Float16 h2_t __attribute__((ext_vector_type(2)));

__device__ __forceinline__ float fast_rcp(float v){ return __builtin_amdgcn_rcpf(v); }
__device__ __forceinline__ float softplus_f(float v){ return fmaxf(v,0.f)+__logf(1.f+__expf(-fabsf(v))); }
__device__ __forceinline__ float sigmoid_f(float v){ return fast_rcp(1.f+__expf(-v)); }
__device__ __forceinline__ float tanh_f(float v){
    float ax=fminf(fabsf(v),15.f); float e=__expf(2.f*ax);
    float r=1.f-2.f*fast_rcp(e+1.f); return copysignf(r,v);
}
__device__ __forceinline__ float pack2(float a,float b){
    h2_t h; h.x=(_Float16)a; h.y=(_Float16)b; return __builtin_bit_cast(float,h);
}
__device__ __forceinline__ float dot2c(float wc,float ac,float acc){
    return __builtin_amdgcn_fdot2(__builtin_bit_cast(h2_t,wc),__builtin_bit_cast(h2_t,ac),acc,false);
}
__device__ __forceinline__ float dot2q(float4 wq,float4 aq,float acc){
    acc=dot2c(wq.x,aq.x,acc); acc=dot2c(wq.y,aq.y,acc);
    acc=dot2c(wq.z,aq.z,acc); acc=dot2c(wq.w,aq.w,acc); return acc;
}
#define DOT4(acc,Wv,Av) acc += (Wv).x*(Av).x + (Wv).y*(Av).y + (Wv).z*(Av).z + (Wv).w*(Av).w
#define PIN4(q) asm volatile("" : "+v"((q).x), "+v"((q).y), "+v"((q).z), "+v"((q).w))

#define V1STR 68   // words per row (16B aligned, odd*4 bank phase)
#define V2STR 68
#define RSTR  34

// One wave per batch. Lane l owns rows {l, 64+l, 128+l} of every layer. No barriers anywhere.
__global__ __launch_bounds__(64, 1)
void ncde_solve(const float* __restrict__ ts, const float* __restrict__ x,
                const float* __restrict__ W0, const float* __restrict__ b0,
                const float* __restrict__ W1, const float* __restrict__ b1,
                const float* __restrict__ W2, const float* __restrict__ b2,
                const float* __restrict__ V0, const float* __restrict__ c0,
                const float* __restrict__ V1, const float* __restrict__ c1,
                const float* __restrict__ V2, const float* __restrict__ c2,
                const float* __restrict__ R, const float* __restrict__ rb,
                float* __restrict__ out)
{
    const int b = blockIdx.x;
    const int l = threadIdx.x;   // lane 0..63

    // ---- LDS ----
    __shared__ __align__(16) float V1L[128*V1STR];   // fp16-packed V1 rows (34.8 KB)
    __shared__ __align__(16) float V2L[192*V2STR];   // fp16-packed V2 rows (52.2 KB)
    __shared__ __align__(16) float RL[32*RSTR];      // fp16-packed R rows
    __shared__ __align__(16) float yH[32],  y2H[32];    // 64 halves
    __shared__ __align__(16) float a0H[64], a1H[64];    // 128 halves
    __shared__ __align__(16) float mH[96];              // 192 halves
    __shared__ __align__(16) float u0H[192], u1H[192];  // 3 x 128 halves
    __shared__ __align__(16) float hA[128];             // fp32 h0 scratch
    __shared__ float slpL[NW*6];
    __shared__ float dtsL[NSTEP];

    // ---- V0 rows {l, 64+l} fp16-packed in registers (64 VGPR) ----
    float4 v0r[2][8];
    {
        #pragma unroll
        for (int r2=0;r2<2;r2++){
            const float4* p = (const float4*)(V0 + (l + 64*r2)*64);
            #pragma unroll
            for (int c=0;c<8;c++){
                float4 a=p[2*c], bq=p[2*c+1];
                float4 r; r.x=pack2(a.x,a.y); r.y=pack2(a.z,a.w); r.z=pack2(bq.x,bq.y); r.w=pack2(bq.z,bq.w);
                v0r[r2][c]=r;
            }
        }
        #pragma unroll
        for (int r2=0;r2<2;r2++){
            #pragma unroll
            for (int c=0;c<8;c++) PIN4(v0r[r2][c]);
        }
    }
    // ---- V1 -> LDS (rows l, 64+l per lane) ----
    #pragma unroll
    for (int r2=0;r2<2;r2++){
        const int row = l + 64*r2;
        const float4* p = (const float4*)(V1 + row*128);
        float4* dst = (float4*)(V1L + row*V1STR);
        #pragma unroll
        for (int c=0;c<16;c++){
            float4 a=p[2*c], bq=p[2*c+1];
            float4 r; r.x=pack2(a.x,a.y); r.y=pack2(a.z,a.w); r.z=pack2(bq.x,bq.y); r.w=pack2(bq.z,bq.w);
            dst[c]=r;
        }
    }
    // ---- V2 -> LDS (rows l, 64+l, 128+l per lane) ----
    #pragma unroll
    for (int r3=0;r3<3;r3++){
        const int row = l + 64*r3;
        const float4* p = (const float4*)(V2 + row*128);
        float4* dst = (float4*)(V2L + row*V2STR);
        #pragma unroll
        for (int c=0;c<16;c++){
            float4 a=p[2*c], bq=p[2*c+1];
            float4 r; r.x=pack2(a.x,a.y); r.y=pack2(a.z,a.w); r.z=pack2(bq.x,bq.y); r.w=pack2(bq.z,bq.w);
            dst[c]=r;
        }
    }
    // ---- R -> LDS (lanes 0..31) ----
    if (l < 32){
        const float4* p = (const float4*)(R + l*64);
        float4* dst = (float4*)(RL + l*RSTR);
        #pragma unroll
        for (int c=0;c<8;c++){
            float4 a=p[2*c], bq=p[2*c+1];
            float4 r; r.x=pack2(a.x,a.y); r.y=pack2(a.z,a.w); r.z=pack2(bq.x,bq.y); r.w=pack2(bq.z,bq.w);
            dst[c]=r;
        }
    }

    const float c0A=c0[l], c0B=c0[64+l];
    const float c1A=c1[l], c1B=c1[64+l];
    const float c2A=c2[l], c2B=c2[64+l], c2C=c2[128+l];
    const float rbl = rb[l & 31];

    const float* tsb = ts + b*TT;
    for (int i=l; i<NSTEP; i+=64) dtsL[i] = tsb[i+1] - tsb[i];

    // ---- log-signature slopes (lanes 0..15) ----
    if (l < NW) {
        const int w = l;
        const float* xs = x + (size_t)(b*TT + w*WINW)*3;
        float x0c[3] = {xs[0], xs[1], xs[2]};
        float prev[3] = {x0c[0], x0c[1], x0c[2]};
        float am01=0.f, am02=0.f, am12=0.f, am10=0.f, am20=0.f, am21=0.f;
        #pragma unroll
        for (int k=0;k<WINW;k++) {
            float cur[3] = {xs[(k+1)*3+0], xs[(k+1)*3+1], xs[(k+1)*3+2]};
            float rel[3], dv[3];
            #pragma unroll
            for (int c=0;c<3;c++){ rel[c]=prev[c]-x0c[c]; dv[c]=cur[c]-prev[c]; }
            am01 += rel[0]*dv[1]; am10 += rel[1]*dv[0];
            am02 += rel[0]*dv[2]; am20 += rel[2]*dv[0];
            am12 += rel[1]*dv[2]; am21 += rel[2]*dv[1];
            prev[0]=cur[0]; prev[1]=cur[1]; prev[2]=cur[2];
        }
        const float invden = 1.f/(tsb[(w+1)*WINW] - tsb[w*WINW]);
        slpL[w*6+0] = (prev[0]-x0c[0])*invden;
        slpL[w*6+1] = (prev[1]-x0c[1])*invden;
        slpL[w*6+2] = (prev[2]-x0c[2])*invden;
        slpL[w*6+3] = 0.5f*(am01-am10)*invden;
        slpL[w*6+4] = 0.5f*(am02-am20)*invden;
        slpL[w*6+5] = 0.5f*(am12-am21)*invden;
    }

    // ---- h0 = init_mlp(x[b,0,:]) fp32 (single wave, in-order LDS) ----
    float h1a, h1b;   // layer-1 softplus values for rows l, 64+l held in regs
    {
        const float* xb = x + (size_t)b*TT*3;
        const float xv0=xb[0], xv1=xb[1], xv2=xb[2];
        #pragma unroll
        for (int r2=0;r2<2;r2++){
            const int row = l + 64*r2;
            float acc = b0[row] + W0[row*3]*xv0 + W0[row*3+1]*xv1 + W0[row*3+2]*xv2;
            hA[row] = softplus_f(acc);
        }
        float accA = b1[l], accB = b1[64+l];
        {
            const float4* wpA = (const float4*)(W1 + l*128);
            const float4* wpB = (const float4*)(W1 + (64+l)*128);
            #pragma unroll 8
            for (int k=0;k<32;k++){
                float4 av=*(const float4*)&hA[4*k];
                float4 wa=wpA[k], wb=wpB[k];
                DOT4(accA,wa,av); DOT4(accB,wb,av);
            }
        }
        h1a = softplus_f(accA); h1b = softplus_f(accB);
        hA[l] = h1a; hA[64+l] = h1b;
    }
    float yreg;
    {
        float acc = b2[l];
        const float4* wp = (const float4*)(W2 + l*128);
        #pragma unroll 8
        for (int k=0;k<32;k++){ float4 wv=wp[k]; float4 av=*(const float4*)&hA[4*k]; DOT4(acc,wv,av); }
        yreg = acc;
        ((_Float16*)yH)[l] = (_Float16)yreg;
    }

    float S0,S1,S2,S3,S4,S5;

    // ---- fused dot helpers (inline LDS streams; no big register arrays) ----
    // V0 (regs) rows {l,64+l} vs one broadcast stream (K=64: 8 f4)
    auto dotV0_1 = [&](const float* aBuf, float& za, float& zb){
        const float4* A=(const float4*)aBuf;
        float p0=0.f,q0=0.f,p1=0.f,q1=0.f;
        #pragma unroll
        for (int j=0;j<8;j+=2){
            float4 a0=A[j], a1=A[j+1];
            p0=dot2q(v0r[0][j],a0,p0); q0=dot2q(v0r[0][j+1],a1,q0);
            p1=dot2q(v0r[1][j],a0,p1); q1=dot2q(v0r[1][j+1],a1,q1);
        }
        za=p0+q0; zb=p1+q1;
    };
    // V0 rows {l,64+l} vs three broadcast tangent streams
    auto dotV0_3 = [&](const float* M0,const float* M1,const float* M2,
                       float& r00,float& r01,float& r02,float& r10,float& r11,float& r12){
        const float4* B0=(const float4*)M0;
        const float4* B1=(const float4*)M1;
        const float4* B2=(const float4*)M2;
        float a00=0.f,a01=0.f,a02=0.f,a10=0.f,a11=0.f,a12=0.f;
        #pragma unroll
        for (int j=0;j<8;j++){
            float4 wa=v0r[0][j], wb=v0r[1][j];
            float4 t0=B0[j], t1=B1[j], t2=B2[j];
            a00=dot2q(wa,t0,a00); a01=dot2q(wa,t1,a01); a02=dot2q(wa,t2,a02);
            a10=dot2q(wb,t0,a10); a11=dot2q(wb,t1,a11); a12=dot2q(wb,t2,a12);
        }
        r00=a00; r01=a01; r02=a02; r10=a10; r11=a11; r12=a12;
    };
    // V1 (LDS) rows {l,64+l} vs one broadcast stream (K=128: 16 f4)
    auto dotV1_1 = [&](const float* aBuf, float& za, float& zb){
        const float4* w0=(const float4*)(V1L + l*V1STR);
        const float4* w1=(const float4*)(V1L + (64+l)*V1STR);
        const float4* A=(const float4*)aBuf;
        float p0=0.f,q0=0.f,p1=0.f,q1=0.f;
        #pragma unroll
        for (int j=0;j<16;j+=2){
            float4 a0=A[j], a1=A[j+1];
            float4 x0=w0[j], x1=w0[j+1], y0=w1[j], y1=w1[j+1];
            p0=dot2q(x0,a0,p0); q0=dot2q(x1,a1,q0);
            p1=dot2q(y0,a0,p1); q1=dot2q(y1,a1,q1);
        }
        za=p0+q0; zb=p1+q1;
    };
    // V1 rows {l,64+l} vs three broadcast tangent streams (weights loaded ONCE)
    auto dotV1_3 = [&](const float* M0,const float* M1,const float* M2,
                       float& r00,float& r01,float& r02,float& r10,float& r11,float& r12){
        const float4* w0=(const float4*)(V1L + l*V1STR);
        const float4* w1=(const float4*)(V1L + (64+l)*V1STR);
        const float4* B0=(const float4*)M0;
        const float4* B1=(const float4*)M1;
        const float4* B2=(const float4*)M2;
        float a00=0.f,a01=0.f,a02=0.f,a10=0.f,a11=0.f,a12=0.f;
        #pragma unroll
        for (int j=0;j<16;j++){
            float4 wa=w0[j], wb=w1[j];
            float4 t0=B0[j], t1=B1[j], t2=B2[j];
            a00=dot2q(wa,t0,a00); a01=dot2q(wa,t1,a01); a02=dot2q(wa,t2,a02);
            a10=dot2q(wb,t0,a10); a11=dot2q(wb,t1,a11); a12=dot2q(wb,t2,a12);
        }
        r00=a00; r01=a01; r02=a02; r10=a10; r11=a11; r12=a12;
    };
    // V2 (LDS) rows {l,64+l,128+l} vs one broadcast stream
    auto dotV2_3row = [&](const float* aBuf, float& r0, float& r1, float& r2){
        const float4* w0=(const float4*)(V2L + l*V2STR);
        const float4* w1=(const float4*)(V2L + (64+l)*V2STR);
        const float4* w2=(const float4*)(V2L + (128+l)*V2STR);
        const float4* A=(const float4*)aBuf;
        float a0=0.f,a1=0.f,a2=0.f;
        #pragma unroll
        for (int j=0;j<16;j++){
            float4 Aj=A[j];
            a0=dot2q(w0[j],Aj,a0); a1=dot2q(w1[j],Aj,a1); a2=dot2q(w2[j],Aj,a2);
        }
        r0=a0; r1=a1; r2=a2;
    };
    // V2 row (LDS, read once) vs two broadcast tangent streams
    auto dotV2_dual = [&](int row, const float* M0, const float* M1, float& ra, float& rbo){
        const float4* w=(const float4*)(V2L + row*V2STR);
        const float4* B0=(const float4*)M0;
        const float4* B1=(const float4*)M1;
        float pa=0.f,qa=0.f,pb=0.f,qb=0.f;
        #pragma unroll
        for (int j=0;j<16;j+=2){
            float4 w0j=w[j], w1j=w[j+1];
            float4 a0=B0[j], a1=B0[j+1], b0q=B1[j], b1q=B1[j+1];
            pa=dot2q(w0j,a0,pa); qa=dot2q(w1j,a1,qa);
            pb=dot2q(w0j,b0q,pb); qb=dot2q(w1j,b1q,qb);
        }
        ra=pa+qa; rbo=pb+qb;
    };

    auto Feval = [&](const float* yBufH) -> float {
        // S1: z0 = V0@y + c0
        float z0a,z0b; dotV0_1(yBufH, z0a, z0b);
        z0a+=c0A; z0b+=c0B;
        float sg0a=sigmoid_f(z0a), sg0b=sigmoid_f(z0b);
        ((_Float16*)a0H)[l]=(_Float16)softplus_f(z0a);
        ((_Float16*)a0H)[64+l]=(_Float16)softplus_f(z0b);
        // S2: z1 = V1@a0 + c1
        float z1a,z1b; dotV1_1(a0H, z1a, z1b);
        z1a+=c1A; z1b+=c1B;
        float sg1a=sigmoid_f(z1a), sg1b=sigmoid_f(z1b);
        ((_Float16*)a1H)[l]=(_Float16)softplus_f(z1a);
        ((_Float16*)a1H)[64+l]=(_Float16)softplus_f(z1b);
        // S3: z2 = V2@a1 + c2 ; m = tanh
        float zA,zB,zC; dotV2_3row(a1H, zA, zB, zC);
        float m0=tanh_f(zA+c2A), m1=tanh_f(zB+c2B), m2=tanh_f(zC+c2C);
        float d0=1.f-m0*m0, d1=1.f-m1*m1, d2=1.f-m2*m2;
        ((_Float16*)mH)[l]=(_Float16)m0; ((_Float16*)mH)[64+l]=(_Float16)m1; ((_Float16*)mH)[128+l]=(_Float16)m2;
        // S4: u0[d] = sig0 ⊙ (V0 @ m[d])
        {
            float r00,r01,r02,r10,r11,r12;
            dotV0_3(mH, mH+32, mH+64, r00,r01,r02,r10,r11,r12);
            ((_Float16*)u0H)[l]     =(_Float16)(sg0a*r00); ((_Float16*)u0H)[64+l] =(_Float16)(sg0b*r10);
            ((_Float16*)u0H)[128+l] =(_Float16)(sg0a*r01); ((_Float16*)u0H)[192+l]=(_Float16)(sg0b*r11);
            ((_Float16*)u0H)[256+l] =(_Float16)(sg0a*r02); ((_Float16*)u0H)[320+l]=(_Float16)(sg0b*r12);
        }
        // S5: u1[d] = sig1 ⊙ (V1 @ u0[d])
        {
            float r00,r01,r02,r10,r11,r12;
            dotV1_3(u0H, u0H+64, u0H+128, r00,r01,r02,r10,r11,r12);
            ((_Float16*)u1H)[l]     =(_Float16)(sg1a*r00); ((_Float16*)u1H)[64+l] =(_Float16)(sg1b*r10);
            ((_Float16*)u1H)[128+l] =(_Float16)(sg1a*r01); ((_Float16*)u1H)[192+l]=(_Float16)(sg1b*r11);
            ((_Float16*)u1H)[256+l] =(_Float16)(sg1a*r02); ((_Float16*)u1H)[320+l]=(_Float16)(sg1b*r12);
        }
        // S6+S7 fused: all six Jf values for output h=l are lane-local (skip-diagonal built in)
        float J1h,J2h,J0h64,J2h64,J0h128,J1h128;
        dotV2_dual(l,      u1H+64, u1H+128, J1h,    J2h);
        dotV2_dual(64+l,   u1H,    u1H+128, J0h64,  J2h64);
        dotV2_dual(128+l,  u1H,    u1H+64,  J0h128, J1h128);
        J1h*=d0; J2h*=d0; J0h64*=d1; J2h64*=d1; J0h128*=d2; J1h128*=d2;
        return m0*S0 + m1*S1 + m2*S2
             + S3*(J0h64 - J1h) + S4*(J0h128 - J2h) + S5*(J1h128 - J2h64);
    };

    auto proj = [&](int stp){
        const float4* w=(const float4*)(RL + (l&31)*RSTR);
        const float4* Y=(const float4*)yH;
        float p=0.f,q=0.f;
        #pragma unroll
        for (int j=0;j<8;j+=2){
            p=dot2q(w[j],   Y[j],   p);
            q=dot2q(w[j+1], Y[j+1], q);
        }
        if (l < 32) out[(size_t)(b*TT + stp)*OUTD + l] = tanh_f(p+q+rbl);
    };

    // ---- Heun scan ----
    for (int step=0; step<NSTEP; ++step){
        proj(step);
        const int w = step >> 3;
        S0=slpL[w*6+0]; S1=slpL[w*6+1]; S2=slpL[w*6+2];
        S3=slpL[w*6+3]; S4=slpL[w*6+4]; S5=slpL[w*6+5];
        const float dtc = dtsL[step];
        float k1 = Feval(yH);
        float y2 = yreg + dtc*k1;
        ((_Float16*)y2H)[l] = (_Float16)y2;
        float k2 = Feval(y2H);
        yreg = yreg + 0.5f*dtc*(k1+k2);
        ((_Float16*)yH)[l] = (_Float16)yreg;
    }
    proj(NSTEP);
}

extern "C" void kernel_launch(void* const* d_in, const int* in_sizes, int n_in,
                              void* d_out, int out_size, void* d_ws, size_t ws_size,
                              hipStream_t stream) {
    const float* ts = (const float*)d_in[0];
    const float* x  = (const float*)d_in[1];
    const float* W0 = (const float*)d_in[2];
    const float* b0 = (const float*)d_in[3];
    const float* W1 = (const float*)d_in[4];
    const float* b1 = (const float*)d_in[5];
    const float* W2 = (const float*)d_in[6];
    const float* b2 = (const float*)d_in[7];
    const float* V0 = (const float*)d_in[8];
    const float* c0 = (const float*)d_in[9];
    const float* V1 = (const float*)d_in[10];
    const float* c1 = (const float*)d_in[11];
    const float* V2 = (const float*)d_in[12];
    const float* c2 = (const float*)d_in[13];
    const float* R  = (const float*)d_in[14];
    const float* rb = (const float*)d_in[15];
    float* out = (float*)d_out;

    ncde_solve<<<dim3(BB), dim3(64), 0, stream>>>(
        ts, x, W0, b0, W1, b1, W2, b2, V0, c0, V1, c1, V2, c2, R, rb, out);
}

// Round 5
// 1426.972 us; speedup vs baseline: 3.7023x; 3.7023x over previous
//
#include <hip/hip_runtime.h>
#include <math.h>

// Problem constants: D=3, H=64, WIN=8, OUT=32, B=128, T=129
#define BB 128
#define TT 129
#define NSTEP 128
#define NW 16
#define WINW 8
#define OUTD 32

typedef _Float16 h2_t __attribute__((ext_vector_type(2)));

__device__ __forceinline__ float fast_rcp(float v){ return __builtin_amdgcn_rcpf(v); }
__device__ __forceinline__ float softplus_f(float v){ return fmaxf(v,0.f)+__logf(1.f+__expf(-fabsf(v))); }
__device__ __forceinline__ float sigmoid_f(float v){ return fast_rcp(1.f+__expf(-v)); }
__device__ __forceinline__ float tanh_f(float v){
    float ax=fminf(fabsf(v),15.f); float e=__expf(2.f*ax);
    float r=1.f-2.f*fast_rcp(e+1.f); return copysignf(r,v);
}
__device__ __forceinline__ float pack2(float a,float b){
    h2_t h; h.x=(_Float16)a; h.y=(_Float16)b; return __builtin_bit_cast(float,h);
}
__device__ __forceinline__ float dot2c(float wc,float ac,float acc){
    return __builtin_amdgcn_fdot2(__builtin_bit_cast(h2_t,wc),__builtin_bit_cast(h2_t,ac),acc,false);
}
__device__ __forceinline__ float dot2q(float4 wq,float4 aq,float acc){
    acc=dot2c(wq.x,aq.x,acc); acc=dot2c(wq.y,aq.y,acc);
    acc=dot2c(wq.z,aq.z,acc); acc=dot2c(wq.w,aq.w,acc); return acc;
}
#define DOT4(acc,Wv,Av) acc += (Wv).x*(Av).x + (Wv).y*(Av).y + (Wv).z*(Av).z + (Wv).w*(Av).w

// One wave per batch. Lane l owns rows {l, 64+l, 128+l} of every layer. No barriers anywhere.
// All weights fp16-packed in LDS with 16B-granule XOR swizzle: granule j of row r lives at
// index j ^ (r&7)  -> lanes 0..7 (which read rows 0..7 at the same j) span all 32 banks.
__global__ __launch_bounds__(64, 1)
void ncde_solve(const float* __restrict__ ts, const float* __restrict__ x,
                const float* __restrict__ W0, const float* __restrict__ b0,
                const float* __restrict__ W1, const float* __restrict__ b1,
                const float* __restrict__ W2, const float* __restrict__ b2,
                const float* __restrict__ V0, const float* __restrict__ c0,
                const float* __restrict__ V1, const float* __restrict__ c1,
                const float* __restrict__ V2, const float* __restrict__ c2,
                const float* __restrict__ R, const float* __restrict__ rb,
                float* __restrict__ out)
{
    const int b = blockIdx.x;
    const int l = threadIdx.x;   // lane 0..63
    const int l7 = l & 7;        // swizzle key (same for rows l, 64+l, 128+l)

    // ---- LDS (natural power-of-2 row strides; conflicts handled by granule XOR swizzle) ----
    __shared__ __align__(16) float V0L[128*32];   // 128 rows x 64 halves  (16 KB)
    __shared__ __align__(16) float V1L[128*64];   // 128 rows x 128 halves (32 KB)
    __shared__ __align__(16) float V2L[192*64];   // 192 rows x 128 halves (48 KB)
    __shared__ __align__(16) float RL[32*32];     // 32 rows x 64 halves   (4 KB)
    __shared__ __align__(16) float yH[32],  y2H[32];    // 64 halves
    __shared__ __align__(16) float a0H[64], a1H[64];    // 128 halves
    __shared__ __align__(16) float mH[96];              // 192 halves (3 x 64)
    __shared__ __align__(16) float u0H[192], u1H[192];  // 3 x 128 halves
    __shared__ __align__(16) float hA[128];             // fp32 h0 scratch
    __shared__ float slpL[NW*6];
    __shared__ float dtsL[NSTEP];

    // ---- stage V0 (rows l, 64+l), swizzled ----
    #pragma unroll
    for (int r2=0;r2<2;r2++){
        const int row = l + 64*r2;
        const float4* p = (const float4*)(V0 + row*64);
        float4* dst = (float4*)(V0L + row*32);
        #pragma unroll
        for (int c=0;c<8;c++){
            float4 a=p[2*c], bq=p[2*c+1];
            float4 r; r.x=pack2(a.x,a.y); r.y=pack2(a.z,a.w); r.z=pack2(bq.x,bq.y); r.w=pack2(bq.z,bq.w);
            dst[c ^ l7]=r;
        }
    }
    // ---- stage V1 (rows l, 64+l), swizzled ----
    #pragma unroll
    for (int r2=0;r2<2;r2++){
        const int row = l + 64*r2;
        const float4* p = (const float4*)(V1 + row*128);
        float4* dst = (float4*)(V1L + row*64);
        #pragma unroll
        for (int c=0;c<16;c++){
            float4 a=p[2*c], bq=p[2*c+1];
            float4 r; r.x=pack2(a.x,a.y); r.y=pack2(a.z,a.w); r.z=pack2(bq.x,bq.y); r.w=pack2(bq.z,bq.w);
            dst[c ^ l7]=r;
        }
    }
    // ---- stage V2 (rows l, 64+l, 128+l), swizzled ----
    #pragma unroll
    for (int r3=0;r3<3;r3++){
        const int row = l + 64*r3;
        const float4* p = (const float4*)(V2 + row*128);
        float4* dst = (float4*)(V2L + row*64);
        #pragma unroll
        for (int c=0;c<16;c++){
            float4 a=p[2*c], bq=p[2*c+1];
            float4 r; r.x=pack2(a.x,a.y); r.y=pack2(a.z,a.w); r.z=pack2(bq.x,bq.y); r.w=pack2(bq.z,bq.w);
            dst[c ^ l7]=r;
        }
    }
    // ---- stage R (lanes 0..31), swizzled ----
    if (l < 32){
        const float4* p = (const float4*)(R + l*64);
        float4* dst = (float4*)(RL + l*32);
        #pragma unroll
        for (int c=0;c<8;c++){
            float4 a=p[2*c], bq=p[2*c+1];
            float4 r; r.x=pack2(a.x,a.y); r.y=pack2(a.z,a.w); r.z=pack2(bq.x,bq.y); r.w=pack2(bq.z,bq.w);
            dst[c ^ l7]=r;
        }
    }

    const float c0A=c0[l], c0B=c0[64+l];
    const float c1A=c1[l], c1B=c1[64+l];
    const float c2A=c2[l], c2B=c2[64+l], c2C=c2[128+l];
    const float rbl = rb[l & 31];

    const float* tsb = ts + b*TT;
    for (int i=l; i<NSTEP; i+=64) dtsL[i] = tsb[i+1] - tsb[i];

    // ---- log-signature slopes (lanes 0..15) ----
    if (l < NW) {
        const int w = l;
        const float* xs = x + (size_t)(b*TT + w*WINW)*3;
        float x0c[3] = {xs[0], xs[1], xs[2]};
        float prev[3] = {x0c[0], x0c[1], x0c[2]};
        float am01=0.f, am02=0.f, am12=0.f, am10=0.f, am20=0.f, am21=0.f;
        #pragma unroll
        for (int k=0;k<WINW;k++) {
            float cur[3] = {xs[(k+1)*3+0], xs[(k+1)*3+1], xs[(k+1)*3+2]};
            float rel[3], dv[3];
            #pragma unroll
            for (int c=0;c<3;c++){ rel[c]=prev[c]-x0c[c]; dv[c]=cur[c]-prev[c]; }
            am01 += rel[0]*dv[1]; am10 += rel[1]*dv[0];
            am02 += rel[0]*dv[2]; am20 += rel[2]*dv[0];
            am12 += rel[1]*dv[2]; am21 += rel[2]*dv[1];
            prev[0]=cur[0]; prev[1]=cur[1]; prev[2]=cur[2];
        }
        const float invden = 1.f/(tsb[(w+1)*WINW] - tsb[w*WINW]);
        slpL[w*6+0] = (prev[0]-x0c[0])*invden;
        slpL[w*6+1] = (prev[1]-x0c[1])*invden;
        slpL[w*6+2] = (prev[2]-x0c[2])*invden;
        slpL[w*6+3] = 0.5f*(am01-am10)*invden;
        slpL[w*6+4] = 0.5f*(am02-am20)*invden;
        slpL[w*6+5] = 0.5f*(am12-am21)*invden;
    }

    // ---- h0 = init_mlp(x[b,0,:]) fp32 (single wave, in-order LDS) ----
    {
        const float* xb = x + (size_t)b*TT*3;
        const float xv0=xb[0], xv1=xb[1], xv2=xb[2];
        #pragma unroll
        for (int r2=0;r2<2;r2++){
            const int row = l + 64*r2;
            float acc = b0[row] + W0[row*3]*xv0 + W0[row*3+1]*xv1 + W0[row*3+2]*xv2;
            hA[row] = softplus_f(acc);
        }
        float accA = b1[l], accB = b1[64+l];
        {
            const float4* wpA = (const float4*)(W1 + l*128);
            const float4* wpB = (const float4*)(W1 + (64+l)*128);
            #pragma unroll 8
            for (int k=0;k<32;k++){
                float4 av=*(const float4*)&hA[4*k];
                float4 wa=wpA[k], wb=wpB[k];
                DOT4(accA,wa,av); DOT4(accB,wb,av);
            }
        }
        float h1a = softplus_f(accA), h1b = softplus_f(accB);
        hA[l] = h1a; hA[64+l] = h1b;
    }
    float yreg;
    {
        float acc = b2[l];
        const float4* wp = (const float4*)(W2 + l*128);
        #pragma unroll 8
        for (int k=0;k<32;k++){ float4 wv=wp[k]; float4 av=*(const float4*)&hA[4*k]; DOT4(acc,wv,av); }
        yreg = acc;
        ((_Float16*)yH)[l] = (_Float16)yreg;
    }

    float S0,S1,S2,S3,S4,S5;

    auto Feval = [&](const float* yBufH) -> float {
        // S1: z0 = V0@y + c0 (rows l, 64+l)
        float z0a, z0b;
        {
            const float4* w0=(const float4*)(V0L + l*32);
            const float4* w1=(const float4*)(V0L + (64+l)*32);
            const float4* A=(const float4*)yBufH;
            float p0=0.f,p1=0.f;
            #pragma unroll 4
            for (int j=0;j<8;j++){
                const int js = j ^ l7;
                float4 aj=A[j];
                p0=dot2q(w0[js],aj,p0); p1=dot2q(w1[js],aj,p1);
            }
            z0a=p0+c0A; z0b=p1+c0B;
        }
        float sg0a=sigmoid_f(z0a), sg0b=sigmoid_f(z0b);
        ((_Float16*)a0H)[l]=(_Float16)softplus_f(z0a);
        ((_Float16*)a0H)[64+l]=(_Float16)softplus_f(z0b);
        // S2: z1 = V1@a0 + c1
        float z1a, z1b;
        {
            const float4* w0=(const float4*)(V1L + l*64);
            const float4* w1=(const float4*)(V1L + (64+l)*64);
            const float4* A=(const float4*)a0H;
            float p0=0.f,p1=0.f;
            #pragma unroll 4
            for (int j=0;j<16;j++){
                const int js = j ^ l7;
                float4 aj=A[j];
                p0=dot2q(w0[js],aj,p0); p1=dot2q(w1[js],aj,p1);
            }
            z1a=p0+c1A; z1b=p1+c1B;
        }
        float sg1a=sigmoid_f(z1a), sg1b=sigmoid_f(z1b);
        ((_Float16*)a1H)[l]=(_Float16)softplus_f(z1a);
        ((_Float16*)a1H)[64+l]=(_Float16)softplus_f(z1b);
        // S3: z2 = V2@a1 + c2 ; m = tanh (rows l, 64+l, 128+l)
        float m0,m1,m2;
        {
            const float4* w0=(const float4*)(V2L + l*64);
            const float4* w1=(const float4*)(V2L + (64+l)*64);
            const float4* w2=(const float4*)(V2L + (128+l)*64);
            const float4* A=(const float4*)a1H;
            float p0=0.f,p1=0.f,p2=0.f;
            #pragma unroll 4
            for (int j=0;j<16;j++){
                const int js = j ^ l7;
                float4 aj=A[j];
                p0=dot2q(w0[js],aj,p0); p1=dot2q(w1[js],aj,p1); p2=dot2q(w2[js],aj,p2);
            }
            m0=tanh_f(p0+c2A); m1=tanh_f(p1+c2B); m2=tanh_f(p2+c2C);
        }
        float d0=1.f-m0*m0, d1=1.f-m1*m1, d2=1.f-m2*m2;
        ((_Float16*)mH)[l]=(_Float16)m0; ((_Float16*)mH)[64+l]=(_Float16)m1; ((_Float16*)mH)[128+l]=(_Float16)m2;
        // S4: u0[d] = sig0 ⊙ (V0 @ m[d]) — 2 rows x 3 tangents, one fused loop
        {
            const float4* w0=(const float4*)(V0L + l*32);
            const float4* w1=(const float4*)(V0L + (64+l)*32);
            const float4* B0=(const float4*)mH;
            const float4* B1=(const float4*)(mH+32);
            const float4* B2=(const float4*)(mH+64);
            float a00=0.f,a01=0.f,a02=0.f,a10=0.f,a11=0.f,a12=0.f;
            #pragma unroll 4
            for (int j=0;j<8;j++){
                const int js = j ^ l7;
                float4 wa=w0[js], wb=w1[js];
                float4 t0=B0[j], t1=B1[j], t2=B2[j];
                a00=dot2q(wa,t0,a00); a01=dot2q(wa,t1,a01); a02=dot2q(wa,t2,a02);
                a10=dot2q(wb,t0,a10); a11=dot2q(wb,t1,a11); a12=dot2q(wb,t2,a12);
            }
            ((_Float16*)u0H)[l]     =(_Float16)(sg0a*a00); ((_Float16*)u0H)[64+l] =(_Float16)(sg0b*a10);
            ((_Float16*)u0H)[128+l] =(_Float16)(sg0a*a01); ((_Float16*)u0H)[192+l]=(_Float16)(sg0b*a11);
            ((_Float16*)u0H)[256+l] =(_Float16)(sg0a*a02); ((_Float16*)u0H)[320+l]=(_Float16)(sg0b*a12);
        }
        // S5: u1[d] = sig1 ⊙ (V1 @ u0[d]) — 2 rows x 3 tangents, one fused loop
        {
            const float4* w0=(const float4*)(V1L + l*64);
            const float4* w1=(const float4*)(V1L + (64+l)*64);
            const float4* B0=(const float4*)u0H;
            const float4* B1=(const float4*)(u0H+64);
            const float4* B2=(const float4*)(u0H+128);
            float a00=0.f,a01=0.f,a02=0.f,a10=0.f,a11=0.f,a12=0.f;
            #pragma unroll 4
            for (int j=0;j<16;j++){
                const int js = j ^ l7;
                float4 wa=w0[js], wb=w1[js];
                float4 t0=B0[j], t1=B1[j], t2=B2[j];
                a00=dot2q(wa,t0,a00); a01=dot2q(wa,t1,a01); a02=dot2q(wa,t2,a02);
                a10=dot2q(wb,t0,a10); a11=dot2q(wb,t1,a11); a12=dot2q(wb,t2,a12);
            }
            ((_Float16*)u1H)[l]     =(_Float16)(sg1a*a00); ((_Float16*)u1H)[64+l] =(_Float16)(sg1b*a10);
            ((_Float16*)u1H)[128+l] =(_Float16)(sg1a*a01); ((_Float16*)u1H)[192+l]=(_Float16)(sg1b*a11);
            ((_Float16*)u1H)[256+l] =(_Float16)(sg1a*a02); ((_Float16*)u1H)[320+l]=(_Float16)(sg1b*a12);
        }
        // S6+S7 fused: one loop, 3 V2 rows x needed tangent pairs (skip-diagonal built in)
        float J1h=0.f,J2h=0.f,J0h64=0.f,J2h64=0.f,J0h128=0.f,J1h128=0.f;
        {
            const float4* wA=(const float4*)(V2L + l*64);
            const float4* wB=(const float4*)(V2L + (64+l)*64);
            const float4* wC=(const float4*)(V2L + (128+l)*64);
            const float4* U0=(const float4*)u1H;
            const float4* U1=(const float4*)(u1H+64);
            const float4* U2=(const float4*)(u1H+128);
            #pragma unroll 4
            for (int j=0;j<16;j++){
                const int js = j ^ l7;
                float4 wa=wA[js], wb=wB[js], wc=wC[js];
                float4 t0=U0[j], t1=U1[j], t2=U2[j];
                J1h   =dot2q(wa,t1,J1h);    J2h   =dot2q(wa,t2,J2h);
                J0h64 =dot2q(wb,t0,J0h64);  J2h64 =dot2q(wb,t2,J2h64);
                J0h128=dot2q(wc,t0,J0h128); J1h128=dot2q(wc,t1,J1h128);
            }
        }
        J1h*=d0; J2h*=d0; J0h64*=d1; J2h64*=d1; J0h128*=d2; J1h128*=d2;
        return m0*S0 + m1*S1 + m2*S2
             + S3*(J0h64 - J1h) + S4*(J0h128 - J2h) + S5*(J1h128 - J2h64);
    };

    auto proj = [&](int stp){
        const float4* w=(const float4*)(RL + (l&31)*32);
        const float4* Y=(const float4*)yH;
        float p=0.f,q=0.f;
        #pragma unroll
        for (int j=0;j<8;j+=2){
            p=dot2q(w[j ^ l7],     Y[j],   p);
            q=dot2q(w[(j+1) ^ l7], Y[j+1], q);
        }
        if (l < 32) out[(size_t)(b*TT + stp)*OUTD + l] = tanh_f(p+q+rbl);
    };

    // ---- Heun scan ----
    for (int step=0; step<NSTEP; ++step){
        proj(step);
        const int w = step >> 3;
        S0=slpL[w*6+0]; S1=slpL[w*6+1]; S2=slpL[w*6+2];
        S3=slpL[w*6+3]; S4=slpL[w*6+4]; S5=slpL[w*6+5];
        const float dtc = dtsL[step];
        float k1 = Feval(yH);
        float y2 = yreg + dtc*k1;
        ((_Float16*)y2H)[l] = (_Float16)y2;
        float k2 = Feval(y2H);
        yreg = yreg + 0.5f*dtc*(k1+k2);
        ((_Float16*)yH)[l] = (_Float16)yreg;
    }
    proj(NSTEP);
}

extern "C" void kernel_launch(void* const* d_in, const int* in_sizes, int n_in,
                              void* d_out, int out_size, void* d_ws, size_t ws_size,
                              hipStream_t stream) {
    const float* ts = (const float*)d_in[0];
    const float* x  = (const float*)d_in[1];
    const float* W0 = (const float*)d_in[2];
    const float* b0 = (const float*)d_in[3];
    const float* W1 = (const float*)d_in[4];
    const float* b1 = (const float*)d_in[5];
    const float* W2 = (const float*)d_in[6];
    const float* b2 = (const float*)d_in[7];
    const float* V0 = (const float*)d_in[8];
    const float* c0 = (const float*)d_in[9];
    const float* V1 = (const float*)d_in[10];
    const float* c1 = (const float*)d_in[11];
    const float* V2 = (const float*)d_in[12];
    const float* c2 = (const float*)d_in[13];
    const float* R  = (const float*)d_in[14];
    const float* rb = (const float*)d_in[15];
    float* out = (float*)d_out;

    ncde_solve<<<dim3(BB), dim3(64), 0, stream>>>(
        ts, x, W0, b0, W1, b1, W2, b2, V0, c0, V1, c1, V2, c2, R, rb, out);
}

// Round 6
// 1234.093 us; speedup vs baseline: 4.2810x; 1.1563x over previous
//
#include <hip/hip_runtime.h>
#include <math.h>

// Problem constants: D=3, H=64, WIN=8, OUT=32, B=128, T=129
#define BB 128
#define TT 129
#define NSTEP 128
#define NW 16
#define WINW 8
#define OUTD 32

typedef _Float16 h2_t __attribute__((ext_vector_type(2)));

__device__ __forceinline__ float fast_rcp(float v){ return __builtin_amdgcn_rcpf(v); }
__device__ __forceinline__ float softplus_f(float v){ return fmaxf(v,0.f)+__logf(1.f+__expf(-fabsf(v))); }
__device__ __forceinline__ float sigmoid_f(float v){ return fast_rcp(1.f+__expf(-v)); }
__device__ __forceinline__ float tanh_f(float v){
    float ax=fminf(fabsf(v),15.f); float e=__expf(2.f*ax);
    float r=1.f-2.f*fast_rcp(e+1.f); return copysignf(r,v);
}
__device__ __forceinline__ float pack2(float a,float b){
    h2_t h; h.x=(_Float16)a; h.y=(_Float16)b; return __builtin_bit_cast(float,h);
}
__device__ __forceinline__ float dot2c(float wc,float ac,float acc){
    return __builtin_amdgcn_fdot2(__builtin_bit_cast(h2_t,wc),__builtin_bit_cast(h2_t,ac),acc,false);
}
__device__ __forceinline__ float dot2q(float4 wq,float4 aq,float acc){
    acc=dot2c(wq.x,aq.x,acc); acc=dot2c(wq.y,aq.y,acc);
    acc=dot2c(wq.z,aq.z,acc); acc=dot2c(wq.w,aq.w,acc); return acc;
}
#define DOT4(acc,Wv,Av) acc += (Wv).x*(Av).x + (Wv).y*(Av).y + (Wv).z*(Av).z + (Wv).w*(Av).w

// 2 waves per batch; thread t owns whole rows (K in-lane, no shuffles, no reductions).
// Weights fp16-packed in LDS, 16B-granule XOR swizzle (granule j of row r at j^(r&7)).
// Rows {t, 64+t, 128+t} all share key t&7 -> every weight read is bank-spread.
__global__ __launch_bounds__(128, 1)
void ncde_solve(const float* __restrict__ ts, const float* __restrict__ x,
                const float* __restrict__ W0, const float* __restrict__ b0,
                const float* __restrict__ W1, const float* __restrict__ b1,
                const float* __restrict__ W2, const float* __restrict__ b2,
                const float* __restrict__ V0, const float* __restrict__ c0,
                const float* __restrict__ V1, const float* __restrict__ c1,
                const float* __restrict__ V2, const float* __restrict__ c2,
                const float* __restrict__ R, const float* __restrict__ rb,
                float* __restrict__ out)
{
    const int b = blockIdx.x;
    const int t = threadIdx.x;   // 0..127 (2 waves)
    const int k7 = t & 7;        // swizzle key for rows {t, 64+t, 128+t}

    __shared__ __align__(16) float V0L[128*32];   // 16 KB
    __shared__ __align__(16) float V1L[128*64];   // 32 KB
    __shared__ __align__(16) float V2L[192*64];   // 48 KB
    __shared__ __align__(16) float RL[32*32];     // 4 KB
    __shared__ __align__(16) float yH[32],  y2H[32];    // 64 halves each
    __shared__ __align__(16) float a0H[64], a1H[64];    // 128 halves each
    __shared__ __align__(16) float mH[96];              // 192 halves
    __shared__ __align__(16) float u0H[192], u1H[192];  // 384 halves each
    __shared__ float sg0Sh[128];
    __shared__ float mF1[64], J0w[64], J2w[64];
    __shared__ float hA[128], hB[128];
    __shared__ float slpL[NW*6];
    __shared__ float dtsL[NSTEP];

    // ---- stage weights (fp16-packed, swizzled) ----
    {   // V0 row t
        const float4* p = (const float4*)(V0 + t*64);
        float4* dst = (float4*)(V0L + t*32);
        #pragma unroll
        for (int c=0;c<8;c++){
            float4 a=p[2*c], bq=p[2*c+1];
            float4 r; r.x=pack2(a.x,a.y); r.y=pack2(a.z,a.w); r.z=pack2(bq.x,bq.y); r.w=pack2(bq.z,bq.w);
            dst[c ^ k7]=r;
        }
    }
    {   // V1 row t
        const float4* p = (const float4*)(V1 + t*128);
        float4* dst = (float4*)(V1L + t*64);
        #pragma unroll
        for (int c=0;c<16;c++){
            float4 a=p[2*c], bq=p[2*c+1];
            float4 r; r.x=pack2(a.x,a.y); r.y=pack2(a.z,a.w); r.z=pack2(bq.x,bq.y); r.w=pack2(bq.z,bq.w);
            dst[c ^ k7]=r;
        }
    }
    {   // V2 row t
        const float4* p = (const float4*)(V2 + t*128);
        float4* dst = (float4*)(V2L + t*64);
        #pragma unroll
        for (int c=0;c<16;c++){
            float4 a=p[2*c], bq=p[2*c+1];
            float4 r; r.x=pack2(a.x,a.y); r.y=pack2(a.z,a.w); r.z=pack2(bq.x,bq.y); r.w=pack2(bq.z,bq.w);
            dst[c ^ k7]=r;
        }
    }
    if (t < 64){ // V2 row 128+t
        const int row = 128+t;
        const float4* p = (const float4*)(V2 + row*128);
        float4* dst = (float4*)(V2L + row*64);
        #pragma unroll
        for (int c=0;c<16;c++){
            float4 a=p[2*c], bq=p[2*c+1];
            float4 r; r.x=pack2(a.x,a.y); r.y=pack2(a.z,a.w); r.z=pack2(bq.x,bq.y); r.w=pack2(bq.z,bq.w);
            dst[c ^ k7]=r;
        }
    }
    if (t < 32){ // R row t
        const float4* p = (const float4*)(R + t*64);
        float4* dst = (float4*)(RL + t*32);
        #pragma unroll
        for (int c=0;c<8;c++){
            float4 a=p[2*c], bq=p[2*c+1];
            float4 r; r.x=pack2(a.x,a.y); r.y=pack2(a.z,a.w); r.z=pack2(bq.x,bq.y); r.w=pack2(bq.z,bq.w);
            dst[c ^ k7]=r;
        }
    }

    const float c0r=c0[t], c1r=c1[t], c2r=c2[t];
    const float c0x = (t<64)? c0[64+t]  : 0.f;
    const float c2x = (t<64)? c2[128+t] : 0.f;
    const float rblr = rb[t & 31];

    const float* tsb = ts + b*TT;
    dtsL[t] = tsb[t+1] - tsb[t];

    // ---- log-signature slopes (threads 0..15) ----
    if (t < NW) {
        const int w = t;
        const float* xs = x + (size_t)(b*TT + w*WINW)*3;
        float x0c[3] = {xs[0], xs[1], xs[2]};
        float prev[3] = {x0c[0], x0c[1], x0c[2]};
        float am01=0.f, am02=0.f, am12=0.f, am10=0.f, am20=0.f, am21=0.f;
        #pragma unroll
        for (int k=0;k<WINW;k++) {
            float cur[3] = {xs[(k+1)*3+0], xs[(k+1)*3+1], xs[(k+1)*3+2]};
            float rel[3], dv[3];
            #pragma unroll
            for (int c=0;c<3;c++){ rel[c]=prev[c]-x0c[c]; dv[c]=cur[c]-prev[c]; }
            am01 += rel[0]*dv[1]; am10 += rel[1]*dv[0];
            am02 += rel[0]*dv[2]; am20 += rel[2]*dv[0];
            am12 += rel[1]*dv[2]; am21 += rel[2]*dv[1];
            prev[0]=cur[0]; prev[1]=cur[1]; prev[2]=cur[2];
        }
        const float invden = 1.f/(tsb[(w+1)*WINW] - tsb[w*WINW]);
        slpL[w*6+0] = (prev[0]-x0c[0])*invden;
        slpL[w*6+1] = (prev[1]-x0c[1])*invden;
        slpL[w*6+2] = (prev[2]-x0c[2])*invden;
        slpL[w*6+3] = 0.5f*(am01-am10)*invden;
        slpL[w*6+4] = 0.5f*(am02-am20)*invden;
        slpL[w*6+5] = 0.5f*(am12-am21)*invden;
    }

    // ---- h0 = init_mlp(x[b,0,:]) fp32, row t per thread ----
    {
        const float* xb = x + (size_t)b*TT*3;
        float acc = b0[t] + W0[t*3]*xb[0] + W0[t*3+1]*xb[1] + W0[t*3+2]*xb[2];
        hA[t] = softplus_f(acc);
    }
    __syncthreads();
    {
        float acc = b1[t];
        const float4* wp = (const float4*)(W1 + t*128);
        #pragma unroll 8
        for (int k=0;k<32;k++){ float4 wv=wp[k]; float4 av=*(const float4*)&hA[4*k]; DOT4(acc,wv,av); }
        hB[t] = softplus_f(acc);
    }
    __syncthreads();
    float yreg = 0.f, k1r = 0.f;
    if (t < 64){
        float acc = b2[t];
        const float4* wp = (const float4*)(W2 + t*128);
        #pragma unroll 8
        for (int k=0;k<32;k++){ float4 wv=wp[k]; float4 av=*(const float4*)&hB[4*k]; DOT4(acc,wv,av); }
        yreg = acc;
        ((_Float16*)yH)[t] = (_Float16)acc;
    }
    __syncthreads();

    // ---- dot helpers (weight rows swizzled; activations broadcast) ----
    auto dot64 = [&](const float* base, int key, const float* act)->float{
        const float4* w=(const float4*)base; const float4* A=(const float4*)act;
        float p=0.f;
        #pragma unroll 4
        for (int j=0;j<8;j++) p=dot2q(w[j^key],A[j],p);
        return p;
    };
    auto dot128 = [&](const float* base, int key, const float* act)->float{
        const float4* w=(const float4*)base; const float4* A=(const float4*)act;
        float p=0.f,q=0.f;
        #pragma unroll 4
        for (int j=0;j<16;j+=2){ p=dot2q(w[j^key],A[j],p); q=dot2q(w[(j+1)^key],A[j+1],q); }
        return p+q;
    };
    auto dot64x3 = [&](const float* base,int key,const float* A0,const float* A1,const float* A2,
                       float& r0,float& r1,float& r2){
        const float4* w=(const float4*)base;
        const float4 *B0=(const float4*)A0,*B1=(const float4*)A1,*B2=(const float4*)A2;
        float a0=0.f,a1=0.f,a2=0.f;
        #pragma unroll 4
        for (int j=0;j<8;j++){ float4 wj=w[j^key]; a0=dot2q(wj,B0[j],a0); a1=dot2q(wj,B1[j],a1); a2=dot2q(wj,B2[j],a2); }
        r0=a0;r1=a1;r2=a2;
    };
    auto dot128x3 = [&](const float* base,int key,const float* A0,const float* A1,const float* A2,
                        float& r0,float& r1,float& r2){
        const float4* w=(const float4*)base;
        const float4 *B0=(const float4*)A0,*B1=(const float4*)A1,*B2=(const float4*)A2;
        float a0=0.f,a1=0.f,a2=0.f;
        #pragma unroll 4
        for (int j=0;j<16;j++){ float4 wj=w[j^key]; a0=dot2q(wj,B0[j],a0); a1=dot2q(wj,B1[j],a1); a2=dot2q(wj,B2[j],a2); }
        r0=a0;r1=a1;r2=a2;
    };
    auto dot128x2 = [&](const float* base,int key,const float* A0,const float* A1,
                        float& r0,float& r1){
        const float4* w=(const float4*)base;
        const float4 *B0=(const float4*)A0,*B1=(const float4*)A1;
        float a0=0.f,a1=0.f;
        #pragma unroll 4
        for (int j=0;j<16;j++){ float4 wj=w[j^key]; a0=dot2q(wj,B0[j],a0); a1=dot2q(wj,B1[j],a1); }
        r0=a0;r1=a1;
    };

    float sg1r=0.f, m_t=0.f, dt_t=0.f, m2x=0.f, dtx=0.f;
    float J1h=0.f, J2h=0.f, J0h128=0.f, J1h128=0.f;

    auto FevalStages = [&](const float* inH, bool first, int step){
        // S1 (Feval1: wave0 does all 128 rows 2-per-lane; wave1 lanes 0..31 project)
        if (first){
            if (t < 64){
                float za = dot64(V0L + t*32,      k7, inH) + c0r;
                float zb = dot64(V0L + (64+t)*32, k7, inH) + c0x;
                sg0Sh[t]    = sigmoid_f(za);
                sg0Sh[64+t] = sigmoid_f(zb);
                ((_Float16*)a0H)[t]    = (_Float16)softplus_f(za);
                ((_Float16*)a0H)[64+t] = (_Float16)softplus_f(zb);
            } else if (t < 96){
                const int r = t & 31;
                float pr = dot64(RL + r*32, r&7, yH) + rblr;
                out[(size_t)(b*TT + step)*OUTD + r] = tanh_f(pr);
            }
        } else {
            float z = dot64(V0L + t*32, k7, inH) + c0r;
            sg0Sh[t] = sigmoid_f(z);
            ((_Float16*)a0H)[t] = (_Float16)softplus_f(z);
        }
        __syncthreads();
        // S2: z1 = V1@a0 + c1 (row t)
        {
            float z = dot128(V1L + t*64, k7, a0H) + c1r;
            sg1r = sigmoid_f(z);
            ((_Float16*)a1H)[t] = (_Float16)softplus_f(z);
        }
        __syncthreads();
        // S3: m = tanh(V2@a1 + c2) (row t; wave0 also row 128+t)
        {
            float z = dot128(V2L + t*64, k7, a1H) + c2r;
            m_t = tanh_f(z); dt_t = 1.f - m_t*m_t;
            ((_Float16*)mH)[t] = (_Float16)m_t;
            if (t < 64){
                float z2 = dot128(V2L + (128+t)*64, k7, a1H) + c2x;
                m2x = tanh_f(z2); dtx = 1.f - m2x*m2x;
                ((_Float16*)mH)[128+t] = (_Float16)m2x;
            } else {
                mF1[t-64] = m_t;   // m1[h] fp32 for S7
            }
        }
        __syncthreads();
        // S4: u0[d] = sig0 ⊙ (V0 @ m[d]) — row t, weights read once for 3 tangents
        {
            float r0,r1,r2;
            dot64x3(V0L + t*32, k7, mH, mH+32, mH+64, r0,r1,r2);
            const float sg0 = sg0Sh[t];
            ((_Float16*)u0H)[t]     = (_Float16)(sg0*r0);
            ((_Float16*)u0H)[128+t] = (_Float16)(sg0*r1);
            ((_Float16*)u0H)[256+t] = (_Float16)(sg0*r2);
        }
        __syncthreads();
        // S5: u1[d] = sig1 ⊙ (V1 @ u0[d])
        {
            float r0,r1,r2;
            dot128x3(V1L + t*64, k7, u0H, u0H+64, u0H+128, r0,r1,r2);
            ((_Float16*)u1H)[t]     = (_Float16)(sg1r*r0);
            ((_Float16*)u1H)[128+t] = (_Float16)(sg1r*r1);
            ((_Float16*)u1H)[256+t] = (_Float16)(sg1r*r2);
        }
        __syncthreads();
        // S6: J[d][row] = dtan ⊙ (V2[row]·u1[d]) — skip-diagonal
        if (t < 64){
            float a,bv;
            dot128x2(V2L + t*64,       k7, u1H+64, u1H+128, a, bv);  // row t: tangents {1,2}
            J1h = dt_t*a;  J2h = dt_t*bv;
            dot128x2(V2L + (128+t)*64, k7, u1H,    u1H+64,  a, bv);  // row 128+t: {0,1}
            J0h128 = dtx*a; J1h128 = dtx*bv;
        } else {
            float a,bv;
            dot128x2(V2L + t*64, k7, u1H, u1H+128, a, bv);           // row 64+h: {0,2}
            J0w[t-64] = dt_t*a; J2w[t-64] = dt_t*bv;
        }
        __syncthreads();
    };

    // ---- Heun scan ----
    for (int step=0; step<NSTEP; ++step){
        const int w = step >> 3;
        const float S0v=slpL[w*6+0], S1v=slpL[w*6+1], S2v=slpL[w*6+2],
                    S3v=slpL[w*6+3], S4v=slpL[w*6+4], S5v=slpL[w*6+5];
        const float dtc = dtsL[step];

        FevalStages(yH, true, step);
        if (t < 64){
            float k = m_t*S0v + mF1[t]*S1v + m2x*S2v
                    + S3v*(J0w[t]   - J1h)
                    + S4v*(J0h128   - J2h)
                    + S5v*(J1h128   - J2w[t]);
            k1r = k;
            float y2 = yreg + dtc*k;
            ((_Float16*)y2H)[t] = (_Float16)y2;
        }
        __syncthreads();

        FevalStages(y2H, false, step);
        if (t < 64){
            float k = m_t*S0v + mF1[t]*S1v + m2x*S2v
                    + S3v*(J0w[t]   - J1h)
                    + S4v*(J0h128   - J2h)
                    + S5v*(J1h128   - J2w[t]);
            yreg = yreg + 0.5f*dtc*(k1r + k);
            ((_Float16*)yH)[t] = (_Float16)yreg;
        }
        __syncthreads();
    }
    // final projection (t = y_{NSTEP})
    if (t >= 64 && t < 96){
        const int r = t & 31;
        float pr = dot64(RL + r*32, r&7, yH) + rblr;
        out[(size_t)(b*TT + NSTEP)*OUTD + r] = tanh_f(pr);
    }
}

extern "C" void kernel_launch(void* const* d_in, const int* in_sizes, int n_in,
                              void* d_out, int out_size, void* d_ws, size_t ws_size,
                              hipStream_t stream) {
    const float* ts = (const float*)d_in[0];
    const float* x  = (const float*)d_in[1];
    const float* W0 = (const float*)d_in[2];
    const float* b0 = (const float*)d_in[3];
    const float* W1 = (const float*)d_in[4];
    const float* b1 = (const float*)d_in[5];
    const float* W2 = (const float*)d_in[6];
    const float* b2 = (const float*)d_in[7];
    const float* V0 = (const float*)d_in[8];
    const float* c0 = (const float*)d_in[9];
    const float* V1 = (const float*)d_in[10];
    const float* c1 = (const float*)d_in[11];
    const float* V2 = (const float*)d_in[12];
    const float* c2 = (const float*)d_in[13];
    const float* R  = (const float*)d_in[14];
    const float* rb = (const float*)d_in[15];
    float* out = (float*)d_out;

    ncde_solve<<<dim3(BB), dim3(128), 0, stream>>>(
        ts, x, W0, b0, W1, b1, W2, b2, V0, c0, V1, c1, V2, c2, R, rb, out);
}

// Round 7
// 687.077 us; speedup vs baseline: 7.6893x; 1.7961x over previous
//
#include <hip/hip_runtime.h>
#include <math.h>

// Problem constants: D=3, H=64, WIN=8, OUT=32, B=128, T=129
#define BB 128
#define TT 129
#define NSTEP 128
#define NW 16
#define WINW 8
#define OUTD 32

typedef _Float16 h2_t __attribute__((ext_vector_type(2)));

__device__ __forceinline__ float fast_rcp(float v){ return __builtin_amdgcn_rcpf(v); }
__device__ __forceinline__ float softplus_f(float v){ return fmaxf(v,0.f)+__logf(1.f+__expf(-fabsf(v))); }
__device__ __forceinline__ float sigmoid_f(float v){ return fast_rcp(1.f+__expf(-v)); }
__device__ __forceinline__ float tanh_f(float v){
    float ax=fminf(fabsf(v),15.f); float e=__expf(2.f*ax);
    float r=1.f-2.f*fast_rcp(e+1.f); return copysignf(r,v);
}
__device__ __forceinline__ float pack2(float a,float b){
    h2_t h; h.x=(_Float16)a; h.y=(_Float16)b; return __builtin_bit_cast(float,h);
}
__device__ __forceinline__ float dot2c(float wc,float ac,float acc){
    return __builtin_amdgcn_fdot2(__builtin_bit_cast(h2_t,wc),__builtin_bit_cast(h2_t,ac),acc,false);
}
__device__ __forceinline__ float dot2q(float4 wq,float4 aq,float acc){
    acc=dot2c(wq.x,aq.x,acc); acc=dot2c(wq.y,aq.y,acc);
    acc=dot2c(wq.z,aq.z,acc); acc=dot2c(wq.w,aq.w,acc); return acc;
}
#define DOT4(acc,Wv,Av) acc += (Wv).x*(Av).x + (Wv).y*(Av).y + (Wv).z*(Av).z + (Wv).w*(Av).w
#define PIN4(q) asm volatile("" : "+v"((q).x), "+v"((q).y), "+v"((q).z), "+v"((q).w))

// DPP cross-lane: VALU-speed (~4cyc) vs ds_swizzle-based __shfl_xor (~120cyc LDS-pipe)
#define DPPF(x,ctrl) __builtin_bit_cast(float, __builtin_amdgcn_update_dpp(0, __builtin_bit_cast(int,(x)), (ctrl), 0xF, 0xF, true))
__device__ __forceinline__ float dpp_xor1(float x){ return DPPF(x,0xB1); }   // quad_perm [1,0,3,2] (involution)
__device__ __forceinline__ float dpp_xor2(float x){ return DPPF(x,0x4E); }   // quad_perm [2,3,0,1] (involution)
__device__ __forceinline__ float dpp_hmir(float x){ return DPPF(x,0x141); }  // row_half_mirror: lane i <- (i&~7)+(7-(i&7))

__global__ __launch_bounds__(256, 1)
void ncde_solve(const float* __restrict__ ts, const float* __restrict__ x,
                const float* __restrict__ W0, const float* __restrict__ b0,
                const float* __restrict__ W1, const float* __restrict__ b1,
                const float* __restrict__ W2, const float* __restrict__ b2,
                const float* __restrict__ V0, const float* __restrict__ c0,
                const float* __restrict__ V1, const float* __restrict__ c1,
                const float* __restrict__ V2, const float* __restrict__ c2,
                const float* __restrict__ R, const float* __restrict__ rb,
                float* __restrict__ out)
{
    const int b = blockIdx.x;
    const int tid = threadIdx.x;
    const int row2 = tid >> 1, half = tid & 1;         // rows 0..127, K halved
    const int row4 = 128 + (tid >> 2), quad = tid & 3; // V2 rows 128..191, K quartered
    const int prow = tid >> 3, poct = tid & 7;         // projection

    __shared__ __align__(16) float RSh[OUTD*68];           // stride 68: kill bank conflicts
    __shared__ __align__(16) float ySh[64], k1Sh[64];
    __shared__ __align__(16) float yp[32], y2p[32];
    __shared__ __align__(16) float a0p[64], a1p[64];
    __shared__ __align__(16) float mp[96];
    __shared__ __align__(16) float u0p[3][64], u1p[3][64];
    __shared__ float mSh[192];
    __shared__ float JfSh[3][192];
    __shared__ float slopesSh[NW][6];
    __shared__ float dtsSh[NSTEP];

    // ---- fp16-packed weight carriers in registers: 24 float4 = 96 VGPRs ----
    float4 v0p4[4];  // V0 half-row  (32 halves)
    float4 v1p4[8];  // V1 half-row  (64 halves)
    float4 v2p4[8];  // V2 rows 0..127 half-row (64 halves)
    float4 v2q4[4];  // V2 rows 128..191 quarter-row (32 halves), rotated groups
    {
        const float4* p0 = (const float4*)(V0 + row2*64 + half*32);
        #pragma unroll
        for (int k=0;k<4;k++){
            float4 a=p0[2*k], c=p0[2*k+1];
            float4 r; r.x=pack2(a.x,a.y); r.y=pack2(a.z,a.w); r.z=pack2(c.x,c.y); r.w=pack2(c.z,c.w);
            v0p4[k]=r;
        }
        const float4* p1 = (const float4*)(V1 + row2*128 + half*64);
        #pragma unroll
        for (int k=0;k<8;k++){
            float4 a=p1[2*k], c=p1[2*k+1];
            float4 r; r.x=pack2(a.x,a.y); r.y=pack2(a.z,a.w); r.z=pack2(c.x,c.y); r.w=pack2(c.z,c.w);
            v1p4[k]=r;
        }
        const float4* p2 = (const float4*)(V2 + row2*128 + half*64);
        #pragma unroll
        for (int k=0;k<8;k++){
            float4 a=p2[2*k], c=p2[2*k+1];
            float4 r; r.x=pack2(a.x,a.y); r.y=pack2(a.z,a.w); r.z=pack2(c.x,c.y); r.w=pack2(c.z,c.w);
            v2p4[k]=r;
        }
        #pragma unroll
        for (int j=0;j<4;j++){
            int g=(quad+j)&3;
            const float4* pg = (const float4*)(V2 + row4*128 + quad*32 + g*8);
            float4 a=pg[0], c=pg[1];
            float4 r; r.x=pack2(a.x,a.y); r.y=pack2(a.z,a.w); r.z=pack2(c.x,c.y); r.w=pack2(c.z,c.w);
            v2q4[j]=r;
        }
        #pragma unroll
        for (int k=0;k<4;k++) PIN4(v0p4[k]);
        #pragma unroll
        for (int k=0;k<8;k++) PIN4(v1p4[k]);
        #pragma unroll
        for (int k=0;k<8;k++) PIN4(v2p4[k]);
        #pragma unroll
        for (int k=0;k<4;k++) PIN4(v2q4[k]);
    }
    const float c0r = c0[row2], c1r = c1[row2], c2a = c2[row2], c2b = c2[row4];
    const float rbp = rb[prow];

    for (int i=tid; i<OUTD*64; i+=256) RSh[(i>>6)*68 + (i&63)] = R[i];
    const float* tsb = ts + b*TT;
    for (int i=tid; i<NSTEP; i+=256) dtsSh[i] = tsb[i+1] - tsb[i];

    // ---- log-signature slopes ----
    if (tid < NW) {
        const int w = tid;
        const float* xs = x + (size_t)(b*TT + w*WINW)*3;
        float x0c[3] = {xs[0], xs[1], xs[2]};
        float prev[3] = {x0c[0], x0c[1], x0c[2]};
        float am01=0.f, am02=0.f, am12=0.f, am10=0.f, am20=0.f, am21=0.f;
        #pragma unroll
        for (int k=0;k<WINW;k++) {
            float cur[3] = {xs[(k+1)*3+0], xs[(k+1)*3+1], xs[(k+1)*3+2]};
            float rel[3], dv[3];
            #pragma unroll
            for (int c=0;c<3;c++){ rel[c]=prev[c]-x0c[c]; dv[c]=cur[c]-prev[c]; }
            am01 += rel[0]*dv[1]; am10 += rel[1]*dv[0];
            am02 += rel[0]*dv[2]; am20 += rel[2]*dv[0];
            am12 += rel[1]*dv[2]; am21 += rel[2]*dv[1];
            prev[0]=cur[0]; prev[1]=cur[1]; prev[2]=cur[2];
        }
        const float invden = 1.f/(tsb[(w+1)*WINW] - tsb[w*WINW]);
        slopesSh[w][0] = (prev[0]-x0c[0])*invden;
        slopesSh[w][1] = (prev[1]-x0c[1])*invden;
        slopesSh[w][2] = (prev[2]-x0c[2])*invden;
        slopesSh[w][3] = 0.5f*(am01-am10)*invden;
        slopesSh[w][4] = 0.5f*(am02-am20)*invden;
        slopesSh[w][5] = 0.5f*(am12-am21)*invden;
    }

    // ---- h0 = init_mlp(x[b,0,:]) (one-time, fp32; mSh/JfSh as scratch) ----
    if (tid < 128) {
        const float xv0 = x[(size_t)b*TT*3+0];
        const float xv1 = x[(size_t)b*TT*3+1];
        const float xv2 = x[(size_t)b*TT*3+2];
        float acc = b0[tid] + W0[tid*3]*xv0 + W0[tid*3+1]*xv1 + W0[tid*3+2]*xv2;
        mSh[tid] = softplus_f(acc);
    }
    __syncthreads();
    if (tid < 128) {
        float acc = b1[tid];
        const float4* r = (const float4*)(W1 + tid*128);
        #pragma unroll 8
        for (int k=0;k<32;k++){ float4 wv=r[k]; float4 av=*(const float4*)&mSh[4*k]; DOT4(acc,wv,av); }
        JfSh[0][tid] = softplus_f(acc);
    }
    __syncthreads();
    if (tid < 64) {
        float acc = b2[tid];
        const float4* r = (const float4*)(W2 + tid*128);
        #pragma unroll 8
        for (int k=0;k<32;k++){ float4 wv=r[k]; float4 av=*(const float4*)&JfSh[0][4*k]; DOT4(acc,wv,av); }
        ySh[tid] = acc;
        float p = dpp_xor1(acc);
        if (!(tid & 1)) yp[tid>>1] = pack2(acc, p);
    }
    __syncthreads();

    // per-lane activation-derivative registers (producer lane == consumer lane)
    float sig0r=0.f, sig1r=0.f, dtanAr=0.f, dtanBr=0.f;

    const int tlo = (tid < 128) ? 1 : 0;  // S6 skip-diagonal: which of {t0,t1} this half computes

    // ---- F(y): fp16 inner, fp32 feedback ----
    auto Feval = [&](const float* ypIn, bool first, float dt, int w) {
        // S1: z0 = V0@y + c0
        {
            float zA=0.f, zB=0.f;
            const float4* yb = (const float4*)ypIn + half*4;
            zA=dot2q(v0p4[0],yb[0],zA); zB=dot2q(v0p4[1],yb[1],zB);
            zA=dot2q(v0p4[2],yb[2],zA); zB=dot2q(v0p4[3],yb[3],zB);
            float z = zA + zB;
            z += dpp_xor1(z);
            z += c0r;
            float a = softplus_f(z);
            sig0r = sigmoid_f(z);
            if (!half) ((_Float16*)a0p)[row2] = (_Float16)a;
        }
        __syncthreads();
        // S2: z1 = V1@a0 + c1
        {
            float zA=0.f, zB=0.f;
            const float4* ab = (const float4*)a0p + half*8;
            #pragma unroll
            for (int k=0;k<4;k++){ zA=dot2q(v1p4[k],ab[k],zA); }
            #pragma unroll
            for (int k=4;k<8;k++){ zB=dot2q(v1p4[k],ab[k],zB); }
            float z = zA + zB;
            z += dpp_xor1(z);
            z += c1r;
            float a = softplus_f(z);
            sig1r = sigmoid_f(z);
            if (!half) ((_Float16*)a1p)[row2] = (_Float16)a;
        }
        __syncthreads();
        // S3: z2 = V2@a1 + c2 ; m = tanh, dtan in regs
        {
            float zA=0.f, zB=0.f;
            const float4* ab = (const float4*)a1p + half*8;
            #pragma unroll
            for (int k=0;k<4;k++){ zA=dot2q(v2p4[k],ab[k],zA); }
            #pragma unroll
            for (int k=4;k<8;k++){ zB=dot2q(v2p4[k],ab[k],zB); }
            float z = zA + zB;
            z += dpp_xor1(z);
            z += c2a;
            float mm = tanh_f(z);
            dtanAr = 1.f - mm*mm;
            if (!half){ mSh[row2]=mm; ((_Float16*)mp)[row2]=(_Float16)mm; }

            float zq = 0.f;
            const float4* a4 = (const float4*)a1p;
            #pragma unroll
            for (int j=0;j<4;j++){ zq=dot2q(v2q4[j], a4[quad*4 + ((quad+j)&3)], zq); }
            zq += dpp_xor1(zq);
            zq += dpp_xor2(zq);
            zq += c2b;
            float mq = tanh_f(zq);
            dtanBr = 1.f - mq*mq;
            if (!quad){ mSh[row4]=mq; ((_Float16*)mp)[row4]=(_Float16)mq; }
        }
        __syncthreads();
        // S4: u0[d] = sig0 * (V0 @ m[d])
        {
            float t0=0.f,t1=0.f,t2=0.f;
            const float4* m0 = (const float4*)mp + half*4;
            const float4* m1 = (const float4*)mp + 8  + half*4;
            const float4* m2 = (const float4*)mp + 16 + half*4;
            #pragma unroll
            for (int k=0;k<4;k++){ t0=dot2q(v0p4[k],m0[k],t0); t1=dot2q(v0p4[k],m1[k],t1); t2=dot2q(v0p4[k],m2[k],t2); }
            t0 += dpp_xor1(t0);
            t1 += dpp_xor1(t1);
            t2 += dpp_xor1(t2);
            if (!half){
                ((_Float16*)&u0p[0][0])[row2]=(_Float16)(sig0r*t0);
                ((_Float16*)&u0p[1][0])[row2]=(_Float16)(sig0r*t1);
                ((_Float16*)&u0p[2][0])[row2]=(_Float16)(sig0r*t2);
            }
        }
        __syncthreads();
        // S5: u1[d] = sig1 * (V1 @ u0[d])
        {
            float t0=0.f,t1=0.f,t2=0.f;
            const float4* q0 = (const float4*)&u0p[0][0] + half*8;
            const float4* q1 = (const float4*)&u0p[1][0] + half*8;
            const float4* q2 = (const float4*)&u0p[2][0] + half*8;
            #pragma unroll
            for (int k=0;k<8;k++){ t0=dot2q(v1p4[k],q0[k],t0); t1=dot2q(v1p4[k],q1[k],t1); t2=dot2q(v1p4[k],q2[k],t2); }
            t0 += dpp_xor1(t0);
            t1 += dpp_xor1(t1);
            t2 += dpp_xor1(t2);
            if (!half){
                ((_Float16*)&u1p[0][0])[row2]=(_Float16)(sig1r*t0);
                ((_Float16*)&u1p[1][0])[row2]=(_Float16)(sig1r*t1);
                ((_Float16*)&u1p[2][0])[row2]=(_Float16)(sig1r*t2);
            }
        }
        __syncthreads();
        // S6: Jf[d] = dtan * (V2 @ u1[d]) — skip-diagonal:
        // rows 0..63 (tid<128) need tangents {1,2}; rows 64..127 (tid>=128) need {0,2};
        // quad rows 128..191 need {0,1}.
        {
            float tl=0.f, t2v=0.f;
            const float4* ql = (const float4*)&u1p[tlo][0] + half*8;
            const float4* q2 = (const float4*)&u1p[2][0]   + half*8;
            #pragma unroll
            for (int k=0;k<8;k++){ tl=dot2q(v2p4[k],ql[k],tl); t2v=dot2q(v2p4[k],q2[k],t2v); }
            tl  += dpp_xor1(tl);
            t2v += dpp_xor1(t2v);
            if (!half){ JfSh[tlo][row2]=dtanAr*tl; JfSh[2][row2]=dtanAr*t2v; }

            float s0=0.f,s1=0.f;
            const float4* w0 = (const float4*)&u1p[0][0];
            const float4* w1 = (const float4*)&u1p[1][0];
            #pragma unroll
            for (int j=0;j<4;j++){
                const int idx = quad*4 + ((quad+j)&3);
                s0=dot2q(v2q4[j],w0[idx],s0); s1=dot2q(v2q4[j],w1[idx],s1);
            }
            s0 += dpp_xor1(s0); s0 += dpp_xor2(s0);
            s1 += dpp_xor1(s1); s1 += dpp_xor2(s1);
            if (!quad){ JfSh[0][row4]=dtanBr*s0; JfSh[1][row4]=dtanBr*s1; }
        }
        __syncthreads();
        // S7 + Heun integrate (fp32, wave 0) + fp16 y re-pack via DPP
        if (tid < 64) {
            const int h = tid;
            const float s0=slopesSh[w][0], s1=slopesSh[w][1], s2=slopesSh[w][2],
                        s3=slopesSh[w][3], s4=slopesSh[w][4], s5=slopesSh[w][5];
            float kk = mSh[h]*s0 + mSh[64+h]*s1 + mSh[128+h]*s2;
            kk += s3*(JfSh[0][64+h]  - JfSh[1][h]);
            kk += s4*(JfSh[0][128+h] - JfSh[2][h]);
            kk += s5*(JfSh[1][128+h] - JfSh[2][64+h]);
            if (first){
                k1Sh[h] = kk;
                float y2 = ySh[h] + dt*kk;
                float p = dpp_xor1(y2);
                if (!(h&1)) y2p[h>>1] = pack2(y2, p);
            } else {
                float yn = ySh[h] + 0.5f*dt*(k1Sh[h] + kk);
                ySh[h] = yn;
                float p = dpp_xor1(yn);
                if (!(h&1)) yp[h>>1] = pack2(yn, p);
            }
        }
        __syncthreads();
    };

    // ---- projection ----
    auto proj = [&](int stp) {
        const float4* rr = (const float4*)(RSh + prow*68 + poct*8);
        const float4* yy = (const float4*)(ySh + poct*8);
        float pacc = 0.f;
        DOT4(pacc, rr[0], yy[0]); DOT4(pacc, rr[1], yy[1]);
        pacc += dpp_xor1(pacc);
        pacc += dpp_xor2(pacc);
        pacc += dpp_hmir(pacc);   // lane poct==0 now holds the full 8-lane sum
        if (!poct) out[(size_t)(b*TT + stp)*OUTD + prow] = tanh_f(pacc + rbp);
    };

    // ---- Heun scan; projection of y_step overlapped with S1 phase ----
    for (int step=0; step<NSTEP; ++step) {
        proj(step);
        const float dt = dtsSh[step];
        const int w = step >> 3;
        Feval(yp,  true,  dt, w);
        Feval(y2p, false, dt, w);
    }
    proj(NSTEP);
}

extern "C" void kernel_launch(void* const* d_in, const int* in_sizes, int n_in,
                              void* d_out, int out_size, void* d_ws, size_t ws_size,
                              hipStream_t stream) {
    const float* ts = (const float*)d_in[0];
    const float* x  = (const float*)d_in[1];
    const float* W0 = (const float*)d_in[2];
    const float* b0 = (const float*)d_in[3];
    const float* W1 = (const float*)d_in[4];
    const float* b1 = (const float*)d_in[5];
    const float* W2 = (const float*)d_in[6];
    const float* b2 = (const float*)d_in[7];
    const float* V0 = (const float*)d_in[8];
    const float* c0 = (const float*)d_in[9];
    const float* V1 = (const float*)d_in[10];
    const float* c1 = (const float*)d_in[11];
    const float* V2 = (const float*)d_in[12];
    const float* c2 = (const float*)d_in[13];
    const float* R  = (const float*)d_in[14];
    const float* rb = (const float*)d_in[15];
    float* out = (float*)d_out;

    ncde_solve<<<dim3(BB), dim3(256), 0, stream>>>(
        ts, x, W0, b0, W1, b1, W2, b2, V0, c0, V1, c1, V2, c2, R, rb, out);
}

// Round 8
// 617.154 us; speedup vs baseline: 8.5605x; 1.1133x over previous
//
#include <hip/hip_runtime.h>
#include <math.h>

// Problem constants: D=3, H=64, WIN=8, OUT=32, B=128, T=129
#define BB 128
#define TT 129
#define NSTEP 128
#define NW 16
#define WINW 8
#define OUTD 32

typedef _Float16 h2_t __attribute__((ext_vector_type(2)));

__device__ __forceinline__ float fast_rcp(float v){ return __builtin_amdgcn_rcpf(v); }
__device__ __forceinline__ float softplus_f(float v){ return fmaxf(v,0.f)+__logf(1.f+__expf(-fabsf(v))); }
__device__ __forceinline__ float sigmoid_f(float v){ return fast_rcp(1.f+__expf(-v)); }
__device__ __forceinline__ float tanh_f(float v){
    float ax=fminf(fabsf(v),15.f); float e=__expf(2.f*ax);
    float r=1.f-2.f*fast_rcp(e+1.f); return copysignf(r,v);
}
__device__ __forceinline__ float pack2(float a,float b){
    h2_t h; h.x=(_Float16)a; h.y=(_Float16)b; return __builtin_bit_cast(float,h);
}
__device__ __forceinline__ float dot2c(float wc,float ac,float acc){
    return __builtin_amdgcn_fdot2(__builtin_bit_cast(h2_t,wc),__builtin_bit_cast(h2_t,ac),acc,false);
}
__device__ __forceinline__ float dot2q(float4 wq,float4 aq,float acc){
    acc=dot2c(wq.x,aq.x,acc); acc=dot2c(wq.y,aq.y,acc);
    acc=dot2c(wq.z,aq.z,acc); acc=dot2c(wq.w,aq.w,acc); return acc;
}
#define DOT4(acc,Wv,Av) acc += (Wv).x*(Av).x + (Wv).y*(Av).y + (Wv).z*(Av).z + (Wv).w*(Av).w
#define PIN4(v) asm volatile("" : "+v"((v).x), "+v"((v).y), "+v"((v).z), "+v"((v).w))

// DPP cross-lane (VALU-speed). quad_perm domain = 4 consecutive lanes — matches q=tid&3 grouping.
#define DPPF(x,ctrl) __builtin_bit_cast(float, __builtin_amdgcn_update_dpp(0, __builtin_bit_cast(int,(x)), (ctrl), 0xF, 0xF, true))
__device__ __forceinline__ float dpp_xor1(float x){ return DPPF(x,0xB1); }   // quad_perm [1,0,3,2]
__device__ __forceinline__ float dpp_xor2(float x){ return DPPF(x,0x4E); }   // quad_perm [2,3,0,1]
__device__ __forceinline__ float dpp_hmir(float x){ return DPPF(x,0x141); }  // row_half_mirror

// Quad-split: lane (r=tid>>2, q=tid&3) owns rows {r, 64+r, 128+r}, K-slice [q*32, q*32+32).
// All J and m terms for output h=r are lane-local -> S6+S7 fused, 6 barriers/Feval.
__global__ __launch_bounds__(256, 1)
void ncde_solve(const float* __restrict__ ts, const float* __restrict__ x,
                const float* __restrict__ W0, const float* __restrict__ b0,
                const float* __restrict__ W1, const float* __restrict__ b1,
                const float* __restrict__ W2, const float* __restrict__ b2,
                const float* __restrict__ V0, const float* __restrict__ c0,
                const float* __restrict__ V1, const float* __restrict__ c1,
                const float* __restrict__ V2, const float* __restrict__ c2,
                const float* __restrict__ R, const float* __restrict__ rb,
                float* __restrict__ out)
{
    const int b = blockIdx.x;
    const int tid = threadIdx.x;
    const int r = tid >> 2, q = tid & 3;
    const int prow = tid >> 3, poct = tid & 7;

    __shared__ __align__(16) float RSh[OUTD*68];
    __shared__ __align__(16) float ySh[64];
    __shared__ __align__(16) float yp[32], y2p[32];      // 64 halves each
    __shared__ __align__(16) float a0H[64], a1H[64];     // 128 halves each
    __shared__ __align__(16) float mpH[96];              // 192 halves (d-major 3x64)
    __shared__ __align__(16) float u0H[192], u1H[192];   // 384 halves (d-major 3x128); fp32 scratch in init
    __shared__ float slopesSh[NW][6];
    __shared__ float dtsSh[NSTEP];

    // ---- fp16-packed quad-slice weight carriers: 24 float4 = 96 VGPR ----
    float4 v0c[2][2], v1c[2][4], v2c[3][4];
    {
        auto pkld = [](const float* src)->float4{
            const float4* p=(const float4*)src;
            float4 a=p[0], c=p[1];
            float4 rr; rr.x=pack2(a.x,a.y); rr.y=pack2(a.z,a.w); rr.z=pack2(c.x,c.y); rr.w=pack2(c.z,c.w);
            return rr;
        };
        #pragma unroll
        for (int i=0;i<2;i++){
            const float* base = V0 + (r+64*i)*64 + q*16;
            v0c[i][0]=pkld(base); v0c[i][1]=pkld(base+8);
        }
        #pragma unroll
        for (int i=0;i<2;i++){
            const float* base = V1 + (r+64*i)*128 + q*32;
            #pragma unroll
            for (int k=0;k<4;k++) v1c[i][k]=pkld(base+8*k);
        }
        #pragma unroll
        for (int i=0;i<3;i++){
            const float* base = V2 + (r+64*i)*128 + q*32;
            #pragma unroll
            for (int k=0;k<4;k++) v2c[i][k]=pkld(base+8*k);
        }
        #pragma unroll
        for (int i=0;i<2;i++){ PIN4(v0c[i][0]); PIN4(v0c[i][1]); }
        #pragma unroll
        for (int i=0;i<2;i++){
            #pragma unroll
            for (int k=0;k<4;k++) PIN4(v1c[i][k]);
        }
        #pragma unroll
        for (int i=0;i<3;i++){
            #pragma unroll
            for (int k=0;k<4;k++) PIN4(v2c[i][k]);
        }
    }
    const float c0A=c0[r], c0B=c0[64+r];
    const float c1A=c1[r], c1B=c1[64+r];
    const float c2A=c2[r], c2B=c2[64+r], c2C=c2[128+r];
    const float rbp = rb[prow];

    for (int i=tid; i<OUTD*64; i+=256) RSh[(i>>6)*68 + (i&63)] = R[i];
    const float* tsb = ts + b*TT;
    for (int i=tid; i<NSTEP; i+=256) dtsSh[i] = tsb[i+1] - tsb[i];

    // ---- log-signature slopes ----
    if (tid < NW) {
        const int w = tid;
        const float* xs = x + (size_t)(b*TT + w*WINW)*3;
        float x0c[3] = {xs[0], xs[1], xs[2]};
        float prev[3] = {x0c[0], x0c[1], x0c[2]};
        float am01=0.f, am02=0.f, am12=0.f, am10=0.f, am20=0.f, am21=0.f;
        #pragma unroll
        for (int k=0;k<WINW;k++) {
            float cur[3] = {xs[(k+1)*3+0], xs[(k+1)*3+1], xs[(k+1)*3+2]};
            float rel[3], dv[3];
            #pragma unroll
            for (int c=0;c<3;c++){ rel[c]=prev[c]-x0c[c]; dv[c]=cur[c]-prev[c]; }
            am01 += rel[0]*dv[1]; am10 += rel[1]*dv[0];
            am02 += rel[0]*dv[2]; am20 += rel[2]*dv[0];
            am12 += rel[1]*dv[2]; am21 += rel[2]*dv[1];
            prev[0]=cur[0]; prev[1]=cur[1]; prev[2]=cur[2];
        }
        const float invden = 1.f/(tsb[(w+1)*WINW] - tsb[w*WINW]);
        slopesSh[w][0] = (prev[0]-x0c[0])*invden;
        slopesSh[w][1] = (prev[1]-x0c[1])*invden;
        slopesSh[w][2] = (prev[2]-x0c[2])*invden;
        slopesSh[w][3] = 0.5f*(am01-am10)*invden;
        slopesSh[w][4] = 0.5f*(am02-am20)*invden;
        slopesSh[w][5] = 0.5f*(am12-am21)*invden;
    }

    // ---- h0 = init_mlp(x[b,0,:]) fp32 (u0H/u1H as scratch) ----
    if (tid < 128) {
        const float xv0 = x[(size_t)b*TT*3+0];
        const float xv1 = x[(size_t)b*TT*3+1];
        const float xv2 = x[(size_t)b*TT*3+2];
        float acc = b0[tid] + W0[tid*3]*xv0 + W0[tid*3+1]*xv1 + W0[tid*3+2]*xv2;
        u0H[tid] = softplus_f(acc);
    }
    __syncthreads();
    if (tid < 128) {
        float acc = b1[tid];
        const float4* rw = (const float4*)(W1 + tid*128);
        #pragma unroll 8
        for (int k=0;k<32;k++){ float4 wv=rw[k]; float4 av=*(const float4*)&u0H[4*k]; DOT4(acc,wv,av); }
        u1H[tid] = softplus_f(acc);
    }
    __syncthreads();
    if (tid < 64) {
        float acc = b2[tid];
        const float4* rw = (const float4*)(W2 + tid*128);
        #pragma unroll 8
        for (int k=0;k<32;k++){ float4 wv=rw[k]; float4 av=*(const float4*)&u1H[4*k]; DOT4(acc,wv,av); }
        ySh[tid] = acc;
        ((_Float16*)yp)[tid] = (_Float16)acc;
    }
    __syncthreads();

    float yreg = ySh[r];    // lane-local state (quad-redundant)
    float k1r = 0.f;
    float S0,S1,S2,S3,S4,S5;

    auto Feval = [&](const float* ypIn, bool first, float dtc) {
        float sig0A,sig0B,sig1A,sig1B,mA,mB,mC,dtA,dtB,dtC;
        // S1: z0 = V0@y + c0  (rows r, 64+r; K-slice q)
        {
            const float4* Y = (const float4*)ypIn + q*2;
            float4 y0=Y[0], y1=Y[1];
            float zA=0.f, zB=0.f;
            zA=dot2q(v0c[0][0],y0,zA); zA=dot2q(v0c[0][1],y1,zA);
            zB=dot2q(v0c[1][0],y0,zB); zB=dot2q(v0c[1][1],y1,zB);
            zA += dpp_xor1(zA); zA += dpp_xor2(zA); zA += c0A;
            zB += dpp_xor1(zB); zB += dpp_xor2(zB); zB += c0B;
            sig0A=sigmoid_f(zA); sig0B=sigmoid_f(zB);
            if (!q){
                ((_Float16*)a0H)[r]    = (_Float16)softplus_f(zA);
                ((_Float16*)a0H)[64+r] = (_Float16)softplus_f(zB);
            }
        }
        __syncthreads();
        // S2: z1 = V1@a0 + c1
        {
            const float4* A = (const float4*)a0H + q*4;
            float4 a0=A[0],a1=A[1],a2=A[2],a3=A[3];
            float zA=0.f, zB=0.f;
            zA=dot2q(v1c[0][0],a0,zA); zA=dot2q(v1c[0][1],a1,zA); zA=dot2q(v1c[0][2],a2,zA); zA=dot2q(v1c[0][3],a3,zA);
            zB=dot2q(v1c[1][0],a0,zB); zB=dot2q(v1c[1][1],a1,zB); zB=dot2q(v1c[1][2],a2,zB); zB=dot2q(v1c[1][3],a3,zB);
            zA += dpp_xor1(zA); zA += dpp_xor2(zA); zA += c1A;
            zB += dpp_xor1(zB); zB += dpp_xor2(zB); zB += c1B;
            sig1A=sigmoid_f(zA); sig1B=sigmoid_f(zB);
            if (!q){
                ((_Float16*)a1H)[r]    = (_Float16)softplus_f(zA);
                ((_Float16*)a1H)[64+r] = (_Float16)softplus_f(zB);
            }
        }
        __syncthreads();
        // S3: m = tanh(V2@a1 + c2)  (rows r, 64+r, 128+r)
        {
            const float4* A = (const float4*)a1H + q*4;
            float4 a0=A[0],a1=A[1],a2=A[2],a3=A[3];
            float zA=0.f, zB=0.f, zC=0.f;
            zA=dot2q(v2c[0][0],a0,zA); zA=dot2q(v2c[0][1],a1,zA); zA=dot2q(v2c[0][2],a2,zA); zA=dot2q(v2c[0][3],a3,zA);
            zB=dot2q(v2c[1][0],a0,zB); zB=dot2q(v2c[1][1],a1,zB); zB=dot2q(v2c[1][2],a2,zB); zB=dot2q(v2c[1][3],a3,zB);
            zC=dot2q(v2c[2][0],a0,zC); zC=dot2q(v2c[2][1],a1,zC); zC=dot2q(v2c[2][2],a2,zC); zC=dot2q(v2c[2][3],a3,zC);
            zA += dpp_xor1(zA); zA += dpp_xor2(zA);
            zB += dpp_xor1(zB); zB += dpp_xor2(zB);
            zC += dpp_xor1(zC); zC += dpp_xor2(zC);
            mA=tanh_f(zA+c2A); mB=tanh_f(zB+c2B); mC=tanh_f(zC+c2C);
            dtA=1.f-mA*mA; dtB=1.f-mB*mB; dtC=1.f-mC*mC;
            if (!q){
                ((_Float16*)mpH)[r]     = (_Float16)mA;
                ((_Float16*)mpH)[64+r]  = (_Float16)mB;
                ((_Float16*)mpH)[128+r] = (_Float16)mC;
            }
        }
        __syncthreads();
        // S4: u0[d] = sig0 ⊙ (V0 @ m[d])
        {
            const float4* M = (const float4*)mpH;
            float4 g00=M[q*2], g01=M[q*2+1];
            float4 g10=M[8+q*2], g11=M[8+q*2+1];
            float4 g20=M[16+q*2], g21=M[16+q*2+1];
            float t0A=0.f,t1A=0.f,t2A=0.f,t0B=0.f,t1B=0.f,t2B=0.f;
            t0A=dot2q(v0c[0][0],g00,t0A); t0A=dot2q(v0c[0][1],g01,t0A);
            t1A=dot2q(v0c[0][0],g10,t1A); t1A=dot2q(v0c[0][1],g11,t1A);
            t2A=dot2q(v0c[0][0],g20,t2A); t2A=dot2q(v0c[0][1],g21,t2A);
            t0B=dot2q(v0c[1][0],g00,t0B); t0B=dot2q(v0c[1][1],g01,t0B);
            t1B=dot2q(v0c[1][0],g10,t1B); t1B=dot2q(v0c[1][1],g11,t1B);
            t2B=dot2q(v0c[1][0],g20,t2B); t2B=dot2q(v0c[1][1],g21,t2B);
            t0A += dpp_xor1(t0A); t0A += dpp_xor2(t0A);
            t1A += dpp_xor1(t1A); t1A += dpp_xor2(t1A);
            t2A += dpp_xor1(t2A); t2A += dpp_xor2(t2A);
            t0B += dpp_xor1(t0B); t0B += dpp_xor2(t0B);
            t1B += dpp_xor1(t1B); t1B += dpp_xor2(t1B);
            t2B += dpp_xor1(t2B); t2B += dpp_xor2(t2B);
            if (!q){
                ((_Float16*)u0H)[r]      = (_Float16)(sig0A*t0A);
                ((_Float16*)u0H)[64+r]   = (_Float16)(sig0B*t0B);
                ((_Float16*)u0H)[128+r]  = (_Float16)(sig0A*t1A);
                ((_Float16*)u0H)[192+r]  = (_Float16)(sig0B*t1B);
                ((_Float16*)u0H)[256+r]  = (_Float16)(sig0A*t2A);
                ((_Float16*)u0H)[320+r]  = (_Float16)(sig0B*t2B);
            }
        }
        __syncthreads();
        // S5: u1[d] = sig1 ⊙ (V1 @ u0[d])
        {
            const float4* U = (const float4*)u0H;
            float4 g0[4],g1[4],g2[4];
            #pragma unroll
            for (int k=0;k<4;k++){ g0[k]=U[q*4+k]; g1[k]=U[16+q*4+k]; g2[k]=U[32+q*4+k]; }
            float t0A=0.f,t1A=0.f,t2A=0.f,t0B=0.f,t1B=0.f,t2B=0.f;
            #pragma unroll
            for (int k=0;k<4;k++){
                float4 wa=v1c[0][k], wb=v1c[1][k];
                t0A=dot2q(wa,g0[k],t0A); t1A=dot2q(wa,g1[k],t1A); t2A=dot2q(wa,g2[k],t2A);
                t0B=dot2q(wb,g0[k],t0B); t1B=dot2q(wb,g1[k],t1B); t2B=dot2q(wb,g2[k],t2B);
            }
            t0A += dpp_xor1(t0A); t0A += dpp_xor2(t0A);
            t1A += dpp_xor1(t1A); t1A += dpp_xor2(t1A);
            t2A += dpp_xor1(t2A); t2A += dpp_xor2(t2A);
            t0B += dpp_xor1(t0B); t0B += dpp_xor2(t0B);
            t1B += dpp_xor1(t1B); t1B += dpp_xor2(t1B);
            t2B += dpp_xor1(t2B); t2B += dpp_xor2(t2B);
            if (!q){
                ((_Float16*)u1H)[r]      = (_Float16)(sig1A*t0A);
                ((_Float16*)u1H)[64+r]   = (_Float16)(sig1B*t0B);
                ((_Float16*)u1H)[128+r]  = (_Float16)(sig1A*t1A);
                ((_Float16*)u1H)[192+r]  = (_Float16)(sig1B*t1B);
                ((_Float16*)u1H)[256+r]  = (_Float16)(sig1A*t2A);
                ((_Float16*)u1H)[320+r]  = (_Float16)(sig1B*t2B);
            }
        }
        __syncthreads();
        // S6+S7 fused: J rows {r,64+r,128+r} x skip-diagonal tangents are ALL lane-local,
        // as are mA,mB,mC -> combine + Heun update with no LDS round-trip, no extra barrier.
        {
            const float4* U = (const float4*)u1H;
            float4 g0[4],g1[4],g2[4];
            #pragma unroll
            for (int k=0;k<4;k++){ g0[k]=U[q*4+k]; g1[k]=U[16+q*4+k]; g2[k]=U[32+q*4+k]; }
            float J1r=0.f,J2r=0.f,J0m=0.f,J2m=0.f,J0t=0.f,J1t=0.f;
            #pragma unroll
            for (int k=0;k<4;k++){
                float4 wa=v2c[0][k], wb=v2c[1][k], wc=v2c[2][k];
                J1r=dot2q(wa,g1[k],J1r); J2r=dot2q(wa,g2[k],J2r);
                J0m=dot2q(wb,g0[k],J0m); J2m=dot2q(wb,g2[k],J2m);
                J0t=dot2q(wc,g0[k],J0t); J1t=dot2q(wc,g1[k],J1t);
            }
            J1r += dpp_xor1(J1r); J1r += dpp_xor2(J1r);
            J2r += dpp_xor1(J2r); J2r += dpp_xor2(J2r);
            J0m += dpp_xor1(J0m); J0m += dpp_xor2(J0m);
            J2m += dpp_xor1(J2m); J2m += dpp_xor2(J2m);
            J0t += dpp_xor1(J0t); J0t += dpp_xor2(J0t);
            J1t += dpp_xor1(J1t); J1t += dpp_xor2(J1t);
            J1r*=dtA; J2r*=dtA; J0m*=dtB; J2m*=dtB; J0t*=dtC; J1t*=dtC;
            float kk = mA*S0 + mB*S1 + mC*S2
                     + S3*(J0m - J1r) + S4*(J0t - J2r) + S5*(J1t - J2m);
            if (first){
                k1r = kk;
                float y2 = yreg + dtc*kk;
                if (!q) ((_Float16*)y2p)[r] = (_Float16)y2;
            } else {
                yreg += 0.5f*dtc*(k1r + kk);
                if (!q){ ((_Float16*)yp)[r] = (_Float16)yreg; ySh[r] = yreg; }
            }
        }
        __syncthreads();
    };

    // ---- projection (fp32, overlapped with S1's interval) ----
    auto proj = [&](int stp) {
        const float4* rr = (const float4*)(RSh + prow*68 + poct*8);
        const float4* yy = (const float4*)(ySh + poct*8);
        float pacc = 0.f;
        DOT4(pacc, rr[0], yy[0]); DOT4(pacc, rr[1], yy[1]);
        pacc += dpp_xor1(pacc);
        pacc += dpp_xor2(pacc);
        pacc += dpp_hmir(pacc);
        if (!poct) out[(size_t)(b*TT + stp)*OUTD + prow] = tanh_f(pacc + rbp);
    };

    // ---- Heun scan ----
    for (int step=0; step<NSTEP; ++step) {
        proj(step);
        const int w = step >> 3;
        S0=slopesSh[w][0]; S1=slopesSh[w][1]; S2=slopesSh[w][2];
        S3=slopesSh[w][3]; S4=slopesSh[w][4]; S5=slopesSh[w][5];
        const float dtc = dtsSh[step];
        Feval(yp,  true,  dtc);
        Feval(y2p, false, dtc);
    }
    proj(NSTEP);
}

extern "C" void kernel_launch(void* const* d_in, const int* in_sizes, int n_in,
                              void* d_out, int out_size, void* d_ws, size_t ws_size,
                              hipStream_t stream) {
    const float* ts = (const float*)d_in[0];
    const float* x  = (const float*)d_in[1];
    const float* W0 = (const float*)d_in[2];
    const float* b0 = (const float*)d_in[3];
    const float* W1 = (const float*)d_in[4];
    const float* b1 = (const float*)d_in[5];
    const float* W2 = (const float*)d_in[6];
    const float* b2 = (const float*)d_in[7];
    const float* V0 = (const float*)d_in[8];
    const float* c0 = (const float*)d_in[9];
    const float* V1 = (const float*)d_in[10];
    const float* c1 = (const float*)d_in[11];
    const float* V2 = (const float*)d_in[12];
    const float* c2 = (const float*)d_in[13];
    const float* R  = (const float*)d_in[14];
    const float* rb = (const float*)d_in[15];
    float* out = (float*)d_out;

    ncde_solve<<<dim3(BB), dim3(256), 0, stream>>>(
        ts, x, W0, b0, W1, b1, W2, b2, V0, c0, V1, c1, V2, c2, R, rb, out);
}